// Round 5
// baseline (386.329 us; speedup 1.0000x reference)
//
#include <hip/hip_runtime.h>
#include <hip/hip_bf16.h>

// Single-head self-attention, B=8 S=2048 E=768, fp32 in/out.
// R9: restore R7's measured-fast K-loop environment (two-stage prologue
//     vmcnt(4)->vmcnt(6), NO unroll pragma on K-loop), keep R8's role-named
//     kernels + persistent tiling, extend persistence to QKV:
//   - gemm_qkv: hw grid 288 x NTILE=2 (ZEXT=0: tiles extend the xy plane),
//     refill prologue issued under the epilogue; VTFUSE tiles defer refill
//     until after the LDS transpose (sm.T aliases staging buffers).
//   - gemm_qk: hw grid 256 x NTILE=2 (ZEXT=1: tiles extend z/batch).
// Sync structure (8-phase, counted vmcnt(6), SFEN, setprio, XCD swizzle)
// unchanged from harness-verified R7.

using short8  = __attribute__((ext_vector_type(8))) short;
using floatx4 = __attribute__((ext_vector_type(4))) float;

typedef const __attribute__((address_space(1))) unsigned short* gas_us;
typedef __attribute__((address_space(3))) unsigned short* las_us;

__device__ __forceinline__ float bf2f(unsigned short u){
  union { unsigned int i; float f; } v; v.i = ((unsigned int)u) << 16; return v.f;
}
__device__ __forceinline__ unsigned short f2bf(float f){
  union { float f; unsigned int i; } v; v.f = f;
  unsigned int r = v.i + 0x7fffu + ((v.i >> 16) & 1u);   // RNE
  return (unsigned short)(r >> 16);
}

// ---------------- prep kernels ----------------

__global__ __launch_bounds__(256) void cast_f32_bf16(const float* __restrict__ in,
                                                     unsigned short* __restrict__ out,
                                                     long n){
  long i = ((long)blockIdx.x * 256 + threadIdx.x) * 4;
  if (i + 3 < n) {
    float4 v = *(const float4*)(in + i);
    uint2 o;
    o.x = (unsigned int)f2bf(v.x) | ((unsigned int)f2bf(v.y) << 16);
    o.y = (unsigned int)f2bf(v.z) | ((unsigned int)f2bf(v.w) << 16);
    *(uint2*)(out + i) = o;
  }
}

// 4 weight matrices [n x n] fp32 row-major -> bf16 transposed, one launch.
__global__ __launch_bounds__(256) void transpose_cast_w4(
    const float* __restrict__ W0, const float* __restrict__ W1,
    const float* __restrict__ W2, const float* __restrict__ W3,
    unsigned short* __restrict__ D0, unsigned short* __restrict__ D1,
    unsigned short* __restrict__ D2, unsigned short* __restrict__ D3, int n){
  __shared__ float tile[64][65];
  const int z = blockIdx.z;
  const float* W = (z == 0) ? W0 : (z == 1) ? W1 : (z == 2) ? W2 : W3;
  unsigned short* Wt = (z == 0) ? D0 : (z == 1) ? D1 : (z == 2) ? D2 : D3;
  int bx = blockIdx.x * 64;     // f base
  int by = blockIdx.y * 64;     // e base
  int tx = threadIdx.x & 63;
  int ty = threadIdx.x >> 6;    // 0..3
  #pragma unroll
  for (int r = ty; r < 64; r += 4)
    tile[r][tx] = W[(long)(by + r) * n + bx + tx];
  __syncthreads();
  #pragma unroll
  for (int r = ty; r < 64; r += 4)
    Wt[(long)(bx + r) * n + by + tx] = f2bf(tile[tx][r]);
}

// ---------------- 256x256 8-phase MFMA GEMM body ----------------
// C[m,n] = alpha * sum_k A[m,k]*Bt[n,k]  (+ bias[n])
// A  : bf16 [M x K] rows stride lda elements (batch stride sA)
// Bt : bf16 [N x K] rows stride ldb elements (batch stride sB)
// C  : bf16 or fp32 (OUTF), ldc leading dim (batch stride sC)
// VTFUSE: tiles with n0>=1536 write transposed to vt[B][E][S].
// NTILE: output tiles per block; ZEXT=1: virtual tiles extend z (batch),
//        ZEXT=0: virtual tiles extend the xy plane.
// Requires: M,N mult of 256; K mult of 128; (hw grid * NTILE) % 8 == 0.

union SMemU {
  struct { unsigned short A[2 * 256 * 64]; unsigned short B[2 * 256 * 64]; } ab;
  unsigned short T[256 * 256];
};

template<int BIASN, int OUTF, int VTFUSE, int NTILE, int ZEXT>
__device__ __forceinline__ void gemm256_body(
    const unsigned short* __restrict__ A,
    const unsigned short* __restrict__ Bt,
    void* __restrict__ Cout,
    const float* __restrict__ bias,
    unsigned short* __restrict__ vt,
    int M, int N, int K, int lda, int ldb, int ldc,
    long sA, long sB, long sC, float alpha)
{
  const int gx = gridDim.x, gy = gridDim.y;
  const int nxy = gx * gy;
  const int nwg_hw = nxy * (int)gridDim.z;
  const int nwgv = nwg_hw * NTILE;
  const int vnxy = ZEXT ? nxy : nxy * NTILE;   // xy-plane size of virtual grid
  const int hwflat = (int)blockIdx.x + gx * (int)blockIdx.y + nxy * (int)blockIdx.z;

  __shared__ __align__(16) SMemU sm;
  unsigned short* Asm = sm.ab.A;
  unsigned short* Bsm = sm.ab.B;

  const int tid  = threadIdx.x;
  const int l    = tid & 63;
  const int wv   = tid >> 6;        // 0..7
  const int wm   = wv >> 2;         // 0..1  (M half of block)
  const int wn   = wv & 3;          // 0..3  (N quarter)
  const int la   = l & 15;
  const int quad = l >> 4;
  const int c0   = quad ^ (l & 7);  // swizzled chunk (row&7 == la&7)

  const long ldaL = lda, ldbL = ldb;

  // staging geometry (loop-invariant)
  const int r8  = l >> 3;                 // 0..7
  const int cg  = (l & 7) ^ r8;           // pre-swizzled global chunk
  const int st0 = wv * 16, st1 = wv * 16 + 8;
  const int ar0 = (st0 >> 6) * 128 + (st0 & 63);
  const int ar1 = (st1 >> 6) * 128 + (st1 & 63);

  las_us dA0 = (las_us)&Asm[ar0 * 64];
  las_us dA1 = (las_us)&Asm[ar1 * 64];
  las_us dB0 = (las_us)&Bsm[ar0 * 64];
  las_us dB1 = (las_us)&Bsm[ar1 * 64];

  const short8* A8 = (const short8*)Asm;   // tile stride 2048 short8
  const short8* B8 = (const short8*)Bsm;
  const int rA = (wm * 128 + la) * 8;
  const int rB = (wn * 64  + la) * 8;

  const int NT = K >> 6;   // K % 128 == 0 so NT even
  const int NI = NT >> 1;

  // per-tile mutable state
  long m0, n0;
  int bz;
  const unsigned short *sA0, *sA1, *sB0, *sB1;

#define MKTILE(V) do{ int flat_ = (V); \
  if (!(nwgv & 7)) flat_ = (flat_ & 7) * (nwgv >> 3) + (flat_ >> 3); \
  bz = flat_ / vnxy; const int rxy_ = flat_ - bz * vnxy; \
  const int by_ = rxy_ / gx; const int bx_ = rxy_ - by_ * gx; \
  m0 = (long)by_ * 256; n0 = (long)bx_ * 256; \
  const unsigned short* Ab_ = A  + (long)bz * sA; \
  const unsigned short* Bb_ = Bt + (long)bz * sB; \
  sA0 = Ab_ + (m0 + ar0 + r8) * ldaL + cg * 8; \
  sA1 = Ab_ + (m0 + ar1 + r8) * ldaL + cg * 8; \
  sB0 = Bb_ + (n0 + ar0 + r8) * ldbL + cg * 8; \
  sB1 = Bb_ + (n0 + ar1 + r8) * ldbL + cg * 8; }while(0)

// stage one 128-row granule (2 x global_load_lds, 16B/lane, linear LDS dest)
#define STG(P0,P1,D0,D1,BO,G,KT,LD) do{ const long _ko=(long)(G)*64*(LD)+(long)(KT)*64; \
  __builtin_amdgcn_global_load_lds((gas_us)((P0)+_ko),(D0)+(BO)+(G)*4096,16,0,0);       \
  __builtin_amdgcn_global_load_lds((gas_us)((P1)+_ko),(D1)+(BO)+(G)*4096,16,0,0);}while(0)
// issue tile0->buf0 (4 granule-pairs) + tile1->buf1 (3 pairs), no waits
#define PROLOG_ISSUE do{ \
  STG(sA0,sA1,dA0,dA1,0,0,0,ldaL);      STG(sB0,sB1,dB0,dB1,0,0,0,ldbL);  \
  STG(sA0,sA1,dA0,dA1,0,1,0,ldaL);      STG(sB0,sB1,dB0,dB1,0,1,0,ldbL);  \
  STG(sA0,sA1,dA0,dA1,16384,0,1,ldaL);  STG(sB0,sB1,dB0,dB1,16384,0,1,ldbL); \
  STG(sA0,sA1,dA0,dA1,16384,1,1,ldaL); }while(0)
// ds_read_b128 fragment loads; BO in short8 units (0 or 2048)
#define LDA(BO,MH) { _Pragma("unroll") for (int mf=0; mf<4; mf++){ \
    a[mf][0]=A8[(BO)+rA+((MH)*4+mf)*128+c0]; a[mf][1]=A8[(BO)+rA+((MH)*4+mf)*128+(c0^4)]; } }
#define LDB(DST,BO,NH) { _Pragma("unroll") for (int nf=0; nf<2; nf++){ \
    DST[nf][0]=B8[(BO)+rB+((NH)*2+nf)*128+c0]; DST[nf][1]=B8[(BO)+rB+((NH)*2+nf)*128+(c0^4)]; } }
// 16 MFMA: one C quadrant x K=64
#define MM(MH,NH,BB) { _Pragma("unroll") for (int mf=0; mf<4; mf++) _Pragma("unroll") for (int nf=0; nf<2; nf++){ \
    acc[(MH)*4+mf][(NH)*2+nf]=__builtin_amdgcn_mfma_f32_16x16x32_bf16(a[mf][0],BB[nf][0],acc[(MH)*4+mf][(NH)*2+nf],0,0,0); \
    acc[(MH)*4+mf][(NH)*2+nf]=__builtin_amdgcn_mfma_f32_16x16x32_bf16(a[mf][1],BB[nf][1],acc[(MH)*4+mf][(NH)*2+nf],0,0,0); } }
#define BAR   __builtin_amdgcn_s_barrier()
#define WLG0  asm volatile("s_waitcnt lgkmcnt(0)")
#define SFEN  __builtin_amdgcn_sched_barrier(0)
#define PRIO1 __builtin_amdgcn_s_setprio(1)
#define PRIO0 __builtin_amdgcn_s_setprio(0)

  floatx4 acc[8][4];
  short8 a[4][2], b0[2][2], b1[2][2];

  // tile-0 prologue: R7's measured two-stage form
  MKTILE(hwflat);
  STG(sA0,sA1,dA0,dA1,0,0,0,ldaL);
  STG(sB0,sB1,dB0,dB1,0,0,0,ldbL);
  STG(sA0,sA1,dA0,dA1,0,1,0,ldaL);
  STG(sB0,sB1,dB0,dB1,0,1,0,ldbL);
  asm volatile("s_waitcnt vmcnt(4)");
  STG(sA0,sA1,dA0,dA1,16384,0,1,ldaL);
  STG(sB0,sB1,dB0,dB1,16384,0,1,ldbL);
  STG(sA0,sA1,dA0,dA1,16384,1,1,ldaL);

  #pragma unroll 1
  for (int tile = 0; tile < NTILE; ++tile) {
    #pragma unroll
    for (int i = 0; i < 8; i++)
      #pragma unroll
      for (int j = 0; j < 4; j++)
        #pragma unroll
        for (int r = 0; r < 4; r++) acc[i][j][r] = 0.0f;

    asm volatile("s_waitcnt vmcnt(6)");   // buf0 (8 oldest) complete
    BAR;

    for (int i = 0; i < NI; i++) {
      const int t1 = 2*i + 1;                                  // always < NT
      const int t2 = (2*i + 2 < NT) ? 2*i + 2 : NT - 1;        // clamped prefetch
      const int t3 = (2*i + 3 < NT) ? 2*i + 3 : NT - 1;

      // P1: read buf0 A-h0 (8) + B-h0 (4); stage buf1 B-g1 (tile t1)
      LDA(0,0); LDB(b0,0,0);
      STG(sB0,sB1,dB0,dB1,16384,1,t1,ldbL);
      asm volatile("s_waitcnt lgkmcnt(8)");
      BAR; WLG0; SFEN; PRIO1; MM(0,0,b0); PRIO0; SFEN; BAR;

      // P2: read buf0 B-h1 (4); stage buf0 A-g0 (tile t2)
      LDB(b1,0,1);
      STG(sA0,sA1,dA0,dA1,0,0,t2,ldaL);
      BAR; WLG0; SFEN; PRIO1; MM(0,1,b1); PRIO0; SFEN; BAR;

      // P3: read buf0 A-h1 (8); stage buf0 B-g0 (tile t2)
      LDA(0,1);
      STG(sB0,sB1,dB0,dB1,0,0,t2,ldbL);
      BAR; WLG0; SFEN; PRIO1; MM(1,1,b1); PRIO0; SFEN; BAR;

      // P4: no reads (b0 held); stage buf0 A-g1 (tile t2); counted vmcnt
      STG(sA0,sA1,dA0,dA1,0,1,t2,ldaL);
      BAR; WLG0; SFEN; PRIO1; MM(1,0,b0); PRIO0; SFEN;
      asm volatile("s_waitcnt vmcnt(6)");
      BAR;

      // P5: read buf1 A-h0 + B-h0; stage buf0 B-g1 (tile t2)
      LDA(2048,0); LDB(b0,2048,0);
      STG(sB0,sB1,dB0,dB1,0,1,t2,ldbL);
      asm volatile("s_waitcnt lgkmcnt(8)");
      BAR; WLG0; SFEN; PRIO1; MM(0,0,b0); PRIO0; SFEN; BAR;

      // P6: read buf1 B-h1; stage buf1 A-g0 (tile t3)
      LDB(b1,2048,1);
      STG(sA0,sA1,dA0,dA1,16384,0,t3,ldaL);
      BAR; WLG0; SFEN; PRIO1; MM(0,1,b1); PRIO0; SFEN; BAR;

      // P7: read buf1 A-h1; stage buf1 B-g0 (tile t3)
      LDA(2048,1);
      STG(sB0,sB1,dB0,dB1,16384,0,t3,ldbL);
      BAR; WLG0; SFEN; PRIO1; MM(1,1,b1); PRIO0; SFEN; BAR;

      // P8: no reads; stage buf1 A-g1 (tile t3); counted vmcnt
      STG(sA0,sA1,dA0,dA1,16384,1,t3,ldaL);
      BAR; WLG0; SFEN; PRIO1; MM(1,0,b0); PRIO0; SFEN;
      asm volatile("s_waitcnt vmcnt(6)");
      BAR;
    }

    asm volatile("s_waitcnt vmcnt(0)");   // drain dangling clamped prefetches
    // all waves past P8's closing BAR -> ds_reads drained; LDS reusable.
    const long em0 = m0, en0 = n0;
    const int  ebz = bz;
    const bool vtile = VTFUSE && (en0 >= 1536);
    if (NTILE > 1 && tile + 1 < NTILE && !vtile) {
      MKTILE(hwflat + (tile + 1) * nwg_hw);
      PROLOG_ISSUE;                       // hidden under the epilogue below
    }

    // ---- V-fused epilogue: transpose 256x256 tile through LDS -> Vt[B][E][S]
    if (vtile) {
      __syncthreads();
      unsigned short* T = sm.T;        // [256][256], XOR-swizzled columns
      #pragma unroll
      for (int mf = 0; mf < 8; mf++) {
        #pragma unroll
        for (int nf = 0; nf < 4; nf++) {
          const int ln = wn * 64 + nf * 16 + la;          // local n (Vt row)
          const int lm = wm * 128 + mf * 16 + quad * 4;   // local m (Vt col base)
          unsigned long long pk = 0;
          #pragma unroll
          for (int r = 0; r < 4; r++) {
            float v = acc[mf][nf][r] * alpha;
            if (BIASN) v += bias[en0 + ln];
            pk |= (unsigned long long)f2bf(v) << (16 * r);
          }
          *(unsigned long long*)&T[ln * 256 + (lm ^ ((ln & 7) << 3))] = pk;
        }
      }
      __syncthreads();
      const int b  = (int)(em0 >> 11);         // batch (2048 tokens each)
      const int s0 = (int)(em0 & 2047);
      const int e0 = (int)(en0 - 1536);
      unsigned short* dst = vt + (long)b * 768 * 2048 + (long)e0 * 2048 + s0;
      const int lr = tid >> 5;                 // 0..15
      const int c  = tid & 31;                 // 16B chunk within row
      #pragma unroll
      for (int i = 0; i < 16; i++) {
        const int ln = i * 16 + lr;
        short8 v = *(const short8*)&T[ln * 256 + ((c * 8) ^ ((ln & 7) << 3))];
        *(short8*)&dst[(long)ln * 2048 + c * 8] = v;
      }
      if (NTILE > 1 && tile + 1 < NTILE) {
        __syncthreads();                 // all waves done reading T
        MKTILE(hwflat + (tile + 1) * nwg_hw);
        PROLOG_ISSUE;                    // waited at next tile-top vmcnt(6)
      }
      continue;
    }

    // epilogue: C/D layout: n = la, m = quad*4 + reg   [measured m89/m91]
    float* Cf = (float*)Cout + (long)ebz * sC;
    unsigned short* Ch = (unsigned short*)Cout + (long)ebz * sC;
    #pragma unroll
    for (int mf = 0; mf < 8; mf++) {
      #pragma unroll
      for (int nf = 0; nf < 4; nf++) {
        #pragma unroll
        for (int r = 0; r < 4; r++) {
          long m = em0 + wm * 128 + mf * 16 + quad * 4 + r;
          long n = en0 + wn * 64  + nf * 16 + la;
          float v = acc[mf][nf][r] * alpha;
          if (BIASN) v += bias[n];
          long idx = m * (long)ldc + n;
          if (OUTF) Cf[idx] = v;
          else      Ch[idx] = f2bf(v);
        }
      }
    }
  }

#undef MKTILE
#undef STG
#undef PROLOG_ISSUE
#undef LDA
#undef LDB
#undef MM
#undef BAR
#undef WLG0
#undef SFEN
#undef PRIO1
#undef PRIO0
}

// ---- role-named kernels (distinct Kernel_Name in rocprof) ----
#define GEMM_ARGS const unsigned short* __restrict__ A, const unsigned short* __restrict__ Bt, \
    void* __restrict__ Cout, const float* __restrict__ bias, unsigned short* __restrict__ vt, \
    int M, int N, int K, int lda, int ldb, int ldc, long sA, long sB, long sC, float alpha
#define GEMM_PASS A, Bt, Cout, bias, vt, M, N, K, lda, ldb, ldc, sA, sB, sC, alpha

__global__ __launch_bounds__(512, 2) void gemm_qkv(GEMM_ARGS){ gemm256_body<1,0,1,2,0>(GEMM_PASS); }
__global__ __launch_bounds__(512, 2) void gemm_qk (GEMM_ARGS){ gemm256_body<0,0,0,2,1>(GEMM_PASS); }
__global__ __launch_bounds__(512, 2) void gemm_pv (GEMM_ARGS){ gemm256_body<0,0,0,1,1>(GEMM_PASS); }
__global__ __launch_bounds__(512, 2) void gemm_o  (GEMM_ARGS){ gemm256_body<1,1,0,1,1>(GEMM_PASS); }

// ---------------- row softmax (in-place, bf16) ----------------
__global__ __launch_bounds__(256) void softmax_rows(unsigned short* __restrict__ S, int cols){
  long row = blockIdx.x;
  unsigned short* p = S + row * (long)cols;
  int tid  = threadIdx.x;
  int wave = tid >> 6;
  int lane = tid & 63;

  uint4 raw = ((const uint4*)p)[tid];   // 8 bf16
  unsigned short* rs = (unsigned short*)&raw;
  float x[8];
  float mx = -1e30f;
  #pragma unroll
  for (int i = 0; i < 8; i++) { x[i] = bf2f(rs[i]); mx = fmaxf(mx, x[i]); }
  #pragma unroll
  for (int off = 32; off >= 1; off >>= 1) mx = fmaxf(mx, __shfl_xor(mx, off, 64));

  __shared__ float smax[4], ssum[4];
  if (lane == 0) smax[wave] = mx;
  __syncthreads();
  mx = fmaxf(fmaxf(smax[0], smax[1]), fmaxf(smax[2], smax[3]));

  float s = 0.0f;
  #pragma unroll
  for (int i = 0; i < 8; i++) { x[i] = __expf(x[i] - mx); s += x[i]; }
  #pragma unroll
  for (int off = 32; off >= 1; off >>= 1) s += __shfl_xor(s, off, 64);
  if (lane == 0) ssum[wave] = s;
  __syncthreads();
  s = ssum[0] + ssum[1] + ssum[2] + ssum[3];
  float inv = 1.0f / s;

  #pragma unroll
  for (int i = 0; i < 8; i++) rs[i] = f2bf(x[i] * inv);
  ((uint4*)p)[tid] = raw;
}

// ---------------- launch ----------------

extern "C" void kernel_launch(void* const* d_in, const int* in_sizes, int n_in,
                              void* d_out, int out_size, void* d_ws, size_t ws_size,
                              hipStream_t stream)
{
  const float* x  = (const float*)d_in[0];
  const float* Wq = (const float*)d_in[1];
  const float* bq = (const float*)d_in[2];
  const float* Wk = (const float*)d_in[3];
  const float* bk = (const float*)d_in[4];
  const float* Wv = (const float*)d_in[5];
  const float* bv = (const float*)d_in[6];
  const float* Wo = (const float*)d_in[7];
  const float* bo = (const float*)d_in[8];

  const int B = 8, S = 2048, E = 768;
  const int F = 3 * E;           // 2304 fused output features
  const long BS = (long)B * S;   // 16384

  char* ws = (char*)d_ws;
  unsigned short* x_bf = (unsigned short*)ws;  ws += BS * E * 2;       // 25.2 MB (also ctx)
  unsigned short* W3t  = (unsigned short*)ws;  ws += (long)F * E * 2;  // 3.5 MB  [2304][768]
  unsigned short* Wot  = (unsigned short*)ws;  ws += (long)E * E * 2;
  float*          bqkv = (float*)ws;           ws += 16384;            // 2304 floats (padded)
  unsigned short* QKVb = (unsigned short*)ws;  ws += BS * F * 2;       // 75.5 MB [16384][2304]
  unsigned short* Vt   = (unsigned short*)ws;  ws += BS * E * 2;       // 25.2 MB [B][E][S]
  unsigned short* Sb   = (unsigned short*)ws;  ws += (long)B * S * S * 2; // 67.1 MB
  unsigned short* Cx   = x_bf;  // ctx aliases x_bf (x_bf dead after QKV gemm)

  if (ws_size < (size_t)((char*)ws - (char*)d_ws)) return;

  const float rsE = 1.0f / sqrtf((float)E);

  cast_f32_bf16<<<(int)((BS * E) / 1024), 256, 0, stream>>>(x, x_bf, BS * E);
  dim3 tg(E / 64, E / 64, 4);
  transpose_cast_w4<<<tg, 256, 0, stream>>>(Wq, Wk, Wv, Wo,
                                            W3t, W3t + (long)E * E, W3t + (long)2 * E * E, Wot, E);
  hipMemcpyAsync(bqkv,         bq, E * sizeof(float), hipMemcpyDeviceToDevice, stream);
  hipMemcpyAsync(bqkv + E,     bk, E * sizeof(float), hipMemcpyDeviceToDevice, stream);
  hipMemcpyAsync(bqkv + 2 * E, bv, E * sizeof(float), hipMemcpyDeviceToDevice, stream);

  // fused QKV = x @ [Wq|Wk|Wv] + [bq|bk|bv] : M=16384 N=2304 K=768
  // hw grid 9x32 = 288 x NTILE=2 (ZEXT=0) -> 576 virtual tiles (%8==0)
  // V-slice (n0>=1536) written transposed to Vt by the fused epilogue.
  dim3 gf(F / 256, (int)(BS / 256) / 2, 1);
  gemm_qkv<<<gf, 512, 0, stream>>>(x_bf, W3t, QKVb, bqkv, Vt,
                                   (int)BS, F, E, E, E, F,
                                   0, 0, 0, 1.0f);

  // Sb = Q K^T / sqrt(E) : strided views of QKVb (lda=ldb=2304)
  // hw grid 8x8x4 = 256 x NTILE=2 (ZEXT=1) -> 512 virtual (%8==0)
  dim3 gs(S / 256, S / 256, B / 2);
  gemm_qk<<<gs, 512, 0, stream>>>(QKVb, QKVb + E, Sb, nullptr, nullptr,
                                  S, S, E, F, F, S,
                                  (long)S * F, (long)S * F, (long)S * S, rsE);

  softmax_rows<<<(int)BS, 256, 0, stream>>>(Sb, S);

  // ctx = softmax(S) @ V : M=2048 N=768 K=2048, grid 3x8x8 = 192
  dim3 gp(E / 256, S / 256, B);
  gemm_pv<<<gp, 512, 0, stream>>>(Sb, Vt, Cx, nullptr, nullptr,
                                  S, E, S, S, S, E,
                                  (long)S * S, (long)E * S, (long)S * E, 1.0f);

  // out = ctx @ Wo + bo (fp32 out) : grid 3x64 = 192
  dim3 g1(E / 256, (int)(BS / 256), 1);
  gemm_o<<<g1, 512, 0, stream>>>(Cx, Wot, (float*)d_out, bo, nullptr,
                                 (int)BS, E, E, E, E, E,
                                 0, 0, 0, 1.0f);
}

// Round 6
// 367.349 us; speedup vs baseline: 1.0517x; 1.0517x over previous
//
#include <hip/hip_runtime.h>
#include <hip/hip_bf16.h>

// Single-head self-attention, B=8 S=2048 E=768, fp32 in/out.
// R10: repair R9's load-imbalance (288 hw blocks x NTILE=2 made 32 CUs run
//      4 tiles serially -> 141us makespan). Rule: persistence only when
//      hw grid = one exact round (<=256 and equal rounds).
//   - gemm_qkv: NTILE=1, fluid grid 576 (2.25 rounds packs better than any
//     persistent split of 576).
//   - gemm_qk: keep 256 x NTILE=2 (exactly 1 block/CU; tile pair shares
//     batch + K-panel).
//   - body unchanged from R9 (R7's two-stage prologue, no K-loop unroll).

using short8  = __attribute__((ext_vector_type(8))) short;
using floatx4 = __attribute__((ext_vector_type(4))) float;

typedef const __attribute__((address_space(1))) unsigned short* gas_us;
typedef __attribute__((address_space(3))) unsigned short* las_us;

__device__ __forceinline__ float bf2f(unsigned short u){
  union { unsigned int i; float f; } v; v.i = ((unsigned int)u) << 16; return v.f;
}
__device__ __forceinline__ unsigned short f2bf(float f){
  union { float f; unsigned int i; } v; v.f = f;
  unsigned int r = v.i + 0x7fffu + ((v.i >> 16) & 1u);   // RNE
  return (unsigned short)(r >> 16);
}

// ---------------- prep kernels ----------------

__global__ __launch_bounds__(256) void cast_f32_bf16(const float* __restrict__ in,
                                                     unsigned short* __restrict__ out,
                                                     long n){
  long i = ((long)blockIdx.x * 256 + threadIdx.x) * 4;
  if (i + 3 < n) {
    float4 v = *(const float4*)(in + i);
    uint2 o;
    o.x = (unsigned int)f2bf(v.x) | ((unsigned int)f2bf(v.y) << 16);
    o.y = (unsigned int)f2bf(v.z) | ((unsigned int)f2bf(v.w) << 16);
    *(uint2*)(out + i) = o;
  }
}

// 4 weight matrices [n x n] fp32 row-major -> bf16 transposed, one launch.
__global__ __launch_bounds__(256) void transpose_cast_w4(
    const float* __restrict__ W0, const float* __restrict__ W1,
    const float* __restrict__ W2, const float* __restrict__ W3,
    unsigned short* __restrict__ D0, unsigned short* __restrict__ D1,
    unsigned short* __restrict__ D2, unsigned short* __restrict__ D3, int n){
  __shared__ float tile[64][65];
  const int z = blockIdx.z;
  const float* W = (z == 0) ? W0 : (z == 1) ? W1 : (z == 2) ? W2 : W3;
  unsigned short* Wt = (z == 0) ? D0 : (z == 1) ? D1 : (z == 2) ? D2 : D3;
  int bx = blockIdx.x * 64;     // f base
  int by = blockIdx.y * 64;     // e base
  int tx = threadIdx.x & 63;
  int ty = threadIdx.x >> 6;    // 0..3
  #pragma unroll
  for (int r = ty; r < 64; r += 4)
    tile[r][tx] = W[(long)(by + r) * n + bx + tx];
  __syncthreads();
  #pragma unroll
  for (int r = ty; r < 64; r += 4)
    Wt[(long)(bx + r) * n + by + tx] = f2bf(tile[tx][r]);
}

// ---------------- 256x256 8-phase MFMA GEMM body ----------------
// C[m,n] = alpha * sum_k A[m,k]*Bt[n,k]  (+ bias[n])
// A  : bf16 [M x K] rows stride lda elements (batch stride sA)
// Bt : bf16 [N x K] rows stride ldb elements (batch stride sB)
// C  : bf16 or fp32 (OUTF), ldc leading dim (batch stride sC)
// VTFUSE: tiles with n0>=1536 write transposed to vt[B][E][S].
// NTILE: output tiles per block; ZEXT=1: virtual tiles extend z (batch),
//        ZEXT=0: virtual tiles extend the xy plane.
// Requires: M,N mult of 256; K mult of 128; (hw grid * NTILE) % 8 == 0.

union SMemU {
  struct { unsigned short A[2 * 256 * 64]; unsigned short B[2 * 256 * 64]; } ab;
  unsigned short T[256 * 256];
};

template<int BIASN, int OUTF, int VTFUSE, int NTILE, int ZEXT>
__device__ __forceinline__ void gemm256_body(
    const unsigned short* __restrict__ A,
    const unsigned short* __restrict__ Bt,
    void* __restrict__ Cout,
    const float* __restrict__ bias,
    unsigned short* __restrict__ vt,
    int M, int N, int K, int lda, int ldb, int ldc,
    long sA, long sB, long sC, float alpha)
{
  const int gx = gridDim.x, gy = gridDim.y;
  const int nxy = gx * gy;
  const int nwg_hw = nxy * (int)gridDim.z;
  const int nwgv = nwg_hw * NTILE;
  const int vnxy = ZEXT ? nxy : nxy * NTILE;   // xy-plane size of virtual grid
  const int hwflat = (int)blockIdx.x + gx * (int)blockIdx.y + nxy * (int)blockIdx.z;

  __shared__ __align__(16) SMemU sm;
  unsigned short* Asm = sm.ab.A;
  unsigned short* Bsm = sm.ab.B;

  const int tid  = threadIdx.x;
  const int l    = tid & 63;
  const int wv   = tid >> 6;        // 0..7
  const int wm   = wv >> 2;         // 0..1  (M half of block)
  const int wn   = wv & 3;          // 0..3  (N quarter)
  const int la   = l & 15;
  const int quad = l >> 4;
  const int c0   = quad ^ (l & 7);  // swizzled chunk (row&7 == la&7)

  const long ldaL = lda, ldbL = ldb;

  // staging geometry (loop-invariant)
  const int r8  = l >> 3;                 // 0..7
  const int cg  = (l & 7) ^ r8;           // pre-swizzled global chunk
  const int st0 = wv * 16, st1 = wv * 16 + 8;
  const int ar0 = (st0 >> 6) * 128 + (st0 & 63);
  const int ar1 = (st1 >> 6) * 128 + (st1 & 63);

  las_us dA0 = (las_us)&Asm[ar0 * 64];
  las_us dA1 = (las_us)&Asm[ar1 * 64];
  las_us dB0 = (las_us)&Bsm[ar0 * 64];
  las_us dB1 = (las_us)&Bsm[ar1 * 64];

  const short8* A8 = (const short8*)Asm;   // tile stride 2048 short8
  const short8* B8 = (const short8*)Bsm;
  const int rA = (wm * 128 + la) * 8;
  const int rB = (wn * 64  + la) * 8;

  const int NT = K >> 6;   // K % 128 == 0 so NT even
  const int NI = NT >> 1;

  // per-tile mutable state
  long m0, n0;
  int bz;
  const unsigned short *sA0, *sA1, *sB0, *sB1;

#define MKTILE(V) do{ int flat_ = (V); \
  if (!(nwgv & 7)) flat_ = (flat_ & 7) * (nwgv >> 3) + (flat_ >> 3); \
  bz = flat_ / vnxy; const int rxy_ = flat_ - bz * vnxy; \
  const int by_ = rxy_ / gx; const int bx_ = rxy_ - by_ * gx; \
  m0 = (long)by_ * 256; n0 = (long)bx_ * 256; \
  const unsigned short* Ab_ = A  + (long)bz * sA; \
  const unsigned short* Bb_ = Bt + (long)bz * sB; \
  sA0 = Ab_ + (m0 + ar0 + r8) * ldaL + cg * 8; \
  sA1 = Ab_ + (m0 + ar1 + r8) * ldaL + cg * 8; \
  sB0 = Bb_ + (n0 + ar0 + r8) * ldbL + cg * 8; \
  sB1 = Bb_ + (n0 + ar1 + r8) * ldbL + cg * 8; }while(0)

// stage one 128-row granule (2 x global_load_lds, 16B/lane, linear LDS dest)
#define STG(P0,P1,D0,D1,BO,G,KT,LD) do{ const long _ko=(long)(G)*64*(LD)+(long)(KT)*64; \
  __builtin_amdgcn_global_load_lds((gas_us)((P0)+_ko),(D0)+(BO)+(G)*4096,16,0,0);       \
  __builtin_amdgcn_global_load_lds((gas_us)((P1)+_ko),(D1)+(BO)+(G)*4096,16,0,0);}while(0)
// issue tile0->buf0 (4 granule-pairs) + tile1->buf1 (3 pairs), no waits
#define PROLOG_ISSUE do{ \
  STG(sA0,sA1,dA0,dA1,0,0,0,ldaL);      STG(sB0,sB1,dB0,dB1,0,0,0,ldbL);  \
  STG(sA0,sA1,dA0,dA1,0,1,0,ldaL);      STG(sB0,sB1,dB0,dB1,0,1,0,ldbL);  \
  STG(sA0,sA1,dA0,dA1,16384,0,1,ldaL);  STG(sB0,sB1,dB0,dB1,16384,0,1,ldbL); \
  STG(sA0,sA1,dA0,dA1,16384,1,1,ldaL); }while(0)
// ds_read_b128 fragment loads; BO in short8 units (0 or 2048)
#define LDA(BO,MH) { _Pragma("unroll") for (int mf=0; mf<4; mf++){ \
    a[mf][0]=A8[(BO)+rA+((MH)*4+mf)*128+c0]; a[mf][1]=A8[(BO)+rA+((MH)*4+mf)*128+(c0^4)]; } }
#define LDB(DST,BO,NH) { _Pragma("unroll") for (int nf=0; nf<2; nf++){ \
    DST[nf][0]=B8[(BO)+rB+((NH)*2+nf)*128+c0]; DST[nf][1]=B8[(BO)+rB+((NH)*2+nf)*128+(c0^4)]; } }
// 16 MFMA: one C quadrant x K=64
#define MM(MH,NH,BB) { _Pragma("unroll") for (int mf=0; mf<4; mf++) _Pragma("unroll") for (int nf=0; nf<2; nf++){ \
    acc[(MH)*4+mf][(NH)*2+nf]=__builtin_amdgcn_mfma_f32_16x16x32_bf16(a[mf][0],BB[nf][0],acc[(MH)*4+mf][(NH)*2+nf],0,0,0); \
    acc[(MH)*4+mf][(NH)*2+nf]=__builtin_amdgcn_mfma_f32_16x16x32_bf16(a[mf][1],BB[nf][1],acc[(MH)*4+mf][(NH)*2+nf],0,0,0); } }
#define BAR   __builtin_amdgcn_s_barrier()
#define WLG0  asm volatile("s_waitcnt lgkmcnt(0)")
#define SFEN  __builtin_amdgcn_sched_barrier(0)
#define PRIO1 __builtin_amdgcn_s_setprio(1)
#define PRIO0 __builtin_amdgcn_s_setprio(0)

  floatx4 acc[8][4];
  short8 a[4][2], b0[2][2], b1[2][2];

  // tile-0 prologue: R7's measured two-stage form
  MKTILE(hwflat);
  STG(sA0,sA1,dA0,dA1,0,0,0,ldaL);
  STG(sB0,sB1,dB0,dB1,0,0,0,ldbL);
  STG(sA0,sA1,dA0,dA1,0,1,0,ldaL);
  STG(sB0,sB1,dB0,dB1,0,1,0,ldbL);
  asm volatile("s_waitcnt vmcnt(4)");
  STG(sA0,sA1,dA0,dA1,16384,0,1,ldaL);
  STG(sB0,sB1,dB0,dB1,16384,0,1,ldbL);
  STG(sA0,sA1,dA0,dA1,16384,1,1,ldaL);

  #pragma unroll 1
  for (int tile = 0; tile < NTILE; ++tile) {
    #pragma unroll
    for (int i = 0; i < 8; i++)
      #pragma unroll
      for (int j = 0; j < 4; j++)
        #pragma unroll
        for (int r = 0; r < 4; r++) acc[i][j][r] = 0.0f;

    asm volatile("s_waitcnt vmcnt(6)");   // buf0 (8 oldest) complete
    BAR;

    for (int i = 0; i < NI; i++) {
      const int t1 = 2*i + 1;                                  // always < NT
      const int t2 = (2*i + 2 < NT) ? 2*i + 2 : NT - 1;        // clamped prefetch
      const int t3 = (2*i + 3 < NT) ? 2*i + 3 : NT - 1;

      // P1: read buf0 A-h0 (8) + B-h0 (4); stage buf1 B-g1 (tile t1)
      LDA(0,0); LDB(b0,0,0);
      STG(sB0,sB1,dB0,dB1,16384,1,t1,ldbL);
      asm volatile("s_waitcnt lgkmcnt(8)");
      BAR; WLG0; SFEN; PRIO1; MM(0,0,b0); PRIO0; SFEN; BAR;

      // P2: read buf0 B-h1 (4); stage buf0 A-g0 (tile t2)
      LDB(b1,0,1);
      STG(sA0,sA1,dA0,dA1,0,0,t2,ldaL);
      BAR; WLG0; SFEN; PRIO1; MM(0,1,b1); PRIO0; SFEN; BAR;

      // P3: read buf0 A-h1 (8); stage buf0 B-g0 (tile t2)
      LDA(0,1);
      STG(sB0,sB1,dB0,dB1,0,0,t2,ldbL);
      BAR; WLG0; SFEN; PRIO1; MM(1,1,b1); PRIO0; SFEN; BAR;

      // P4: no reads (b0 held); stage buf0 A-g1 (tile t2); counted vmcnt
      STG(sA0,sA1,dA0,dA1,0,1,t2,ldaL);
      BAR; WLG0; SFEN; PRIO1; MM(1,0,b0); PRIO0; SFEN;
      asm volatile("s_waitcnt vmcnt(6)");
      BAR;

      // P5: read buf1 A-h0 + B-h0; stage buf0 B-g1 (tile t2)
      LDA(2048,0); LDB(b0,2048,0);
      STG(sB0,sB1,dB0,dB1,0,1,t2,ldbL);
      asm volatile("s_waitcnt lgkmcnt(8)");
      BAR; WLG0; SFEN; PRIO1; MM(0,0,b0); PRIO0; SFEN; BAR;

      // P6: read buf1 B-h1; stage buf1 A-g0 (tile t3)
      LDB(b1,2048,1);
      STG(sA0,sA1,dA0,dA1,16384,0,t3,ldaL);
      BAR; WLG0; SFEN; PRIO1; MM(0,1,b1); PRIO0; SFEN; BAR;

      // P7: read buf1 A-h1; stage buf1 B-g0 (tile t3)
      LDA(2048,1);
      STG(sB0,sB1,dB0,dB1,16384,0,t3,ldbL);
      BAR; WLG0; SFEN; PRIO1; MM(1,1,b1); PRIO0; SFEN; BAR;

      // P8: no reads; stage buf1 A-g1 (tile t3); counted vmcnt
      STG(sA0,sA1,dA0,dA1,16384,1,t3,ldaL);
      BAR; WLG0; SFEN; PRIO1; MM(1,0,b0); PRIO0; SFEN;
      asm volatile("s_waitcnt vmcnt(6)");
      BAR;
    }

    asm volatile("s_waitcnt vmcnt(0)");   // drain dangling clamped prefetches
    // all waves past P8's closing BAR -> ds_reads drained; LDS reusable.
    const long em0 = m0, en0 = n0;
    const int  ebz = bz;
    const bool vtile = VTFUSE && (en0 >= 1536);
    if (NTILE > 1 && tile + 1 < NTILE && !vtile) {
      MKTILE(hwflat + (tile + 1) * nwg_hw);
      PROLOG_ISSUE;                       // hidden under the epilogue below
    }

    // ---- V-fused epilogue: transpose 256x256 tile through LDS -> Vt[B][E][S]
    if (vtile) {
      __syncthreads();
      unsigned short* T = sm.T;        // [256][256], XOR-swizzled columns
      #pragma unroll
      for (int mf = 0; mf < 8; mf++) {
        #pragma unroll
        for (int nf = 0; nf < 4; nf++) {
          const int ln = wn * 64 + nf * 16 + la;          // local n (Vt row)
          const int lm = wm * 128 + mf * 16 + quad * 4;   // local m (Vt col base)
          unsigned long long pk = 0;
          #pragma unroll
          for (int r = 0; r < 4; r++) {
            float v = acc[mf][nf][r] * alpha;
            if (BIASN) v += bias[en0 + ln];
            pk |= (unsigned long long)f2bf(v) << (16 * r);
          }
          *(unsigned long long*)&T[ln * 256 + (lm ^ ((ln & 7) << 3))] = pk;
        }
      }
      __syncthreads();
      const int b  = (int)(em0 >> 11);         // batch (2048 tokens each)
      const int s0 = (int)(em0 & 2047);
      const int e0 = (int)(en0 - 1536);
      unsigned short* dst = vt + (long)b * 768 * 2048 + (long)e0 * 2048 + s0;
      const int lr = tid >> 5;                 // 0..15
      const int c  = tid & 31;                 // 16B chunk within row
      #pragma unroll
      for (int i = 0; i < 16; i++) {
        const int ln = i * 16 + lr;
        short8 v = *(const short8*)&T[ln * 256 + ((c * 8) ^ ((ln & 7) << 3))];
        *(short8*)&dst[(long)ln * 2048 + c * 8] = v;
      }
      if (NTILE > 1 && tile + 1 < NTILE) {
        __syncthreads();                 // all waves done reading T
        MKTILE(hwflat + (tile + 1) * nwg_hw);
        PROLOG_ISSUE;                    // waited at next tile-top vmcnt(6)
      }
      continue;
    }

    // epilogue: C/D layout: n = la, m = quad*4 + reg   [measured m89/m91]
    float* Cf = (float*)Cout + (long)ebz * sC;
    unsigned short* Ch = (unsigned short*)Cout + (long)ebz * sC;
    #pragma unroll
    for (int mf = 0; mf < 8; mf++) {
      #pragma unroll
      for (int nf = 0; nf < 4; nf++) {
        #pragma unroll
        for (int r = 0; r < 4; r++) {
          long m = em0 + wm * 128 + mf * 16 + quad * 4 + r;
          long n = en0 + wn * 64  + nf * 16 + la;
          float v = acc[mf][nf][r] * alpha;
          if (BIASN) v += bias[n];
          long idx = m * (long)ldc + n;
          if (OUTF) Cf[idx] = v;
          else      Ch[idx] = f2bf(v);
        }
      }
    }
  }

#undef MKTILE
#undef STG
#undef PROLOG_ISSUE
#undef LDA
#undef LDB
#undef MM
#undef BAR
#undef WLG0
#undef SFEN
#undef PRIO1
#undef PRIO0
}

// ---- role-named kernels (distinct Kernel_Name in rocprof) ----
#define GEMM_ARGS const unsigned short* __restrict__ A, const unsigned short* __restrict__ Bt, \
    void* __restrict__ Cout, const float* __restrict__ bias, unsigned short* __restrict__ vt, \
    int M, int N, int K, int lda, int ldb, int ldc, long sA, long sB, long sC, float alpha
#define GEMM_PASS A, Bt, Cout, bias, vt, M, N, K, lda, ldb, ldc, sA, sB, sC, alpha

__global__ __launch_bounds__(512, 2) void gemm_qkv(GEMM_ARGS){ gemm256_body<1,0,1,1,0>(GEMM_PASS); }
__global__ __launch_bounds__(512, 2) void gemm_qk (GEMM_ARGS){ gemm256_body<0,0,0,2,1>(GEMM_PASS); }
__global__ __launch_bounds__(512, 2) void gemm_pv (GEMM_ARGS){ gemm256_body<0,0,0,1,1>(GEMM_PASS); }
__global__ __launch_bounds__(512, 2) void gemm_o  (GEMM_ARGS){ gemm256_body<1,1,0,1,1>(GEMM_PASS); }

// ---------------- row softmax (in-place, bf16) ----------------
__global__ __launch_bounds__(256) void softmax_rows(unsigned short* __restrict__ S, int cols){
  long row = blockIdx.x;
  unsigned short* p = S + row * (long)cols;
  int tid  = threadIdx.x;
  int wave = tid >> 6;
  int lane = tid & 63;

  uint4 raw = ((const uint4*)p)[tid];   // 8 bf16
  unsigned short* rs = (unsigned short*)&raw;
  float x[8];
  float mx = -1e30f;
  #pragma unroll
  for (int i = 0; i < 8; i++) { x[i] = bf2f(rs[i]); mx = fmaxf(mx, x[i]); }
  #pragma unroll
  for (int off = 32; off >= 1; off >>= 1) mx = fmaxf(mx, __shfl_xor(mx, off, 64));

  __shared__ float smax[4], ssum[4];
  if (lane == 0) smax[wave] = mx;
  __syncthreads();
  mx = fmaxf(fmaxf(smax[0], smax[1]), fmaxf(smax[2], smax[3]));

  float s = 0.0f;
  #pragma unroll
  for (int i = 0; i < 8; i++) { x[i] = __expf(x[i] - mx); s += x[i]; }
  #pragma unroll
  for (int off = 32; off >= 1; off >>= 1) s += __shfl_xor(s, off, 64);
  if (lane == 0) ssum[wave] = s;
  __syncthreads();
  s = ssum[0] + ssum[1] + ssum[2] + ssum[3];
  float inv = 1.0f / s;

  #pragma unroll
  for (int i = 0; i < 8; i++) rs[i] = f2bf(x[i] * inv);
  ((uint4*)p)[tid] = raw;
}

// ---------------- launch ----------------

extern "C" void kernel_launch(void* const* d_in, const int* in_sizes, int n_in,
                              void* d_out, int out_size, void* d_ws, size_t ws_size,
                              hipStream_t stream)
{
  const float* x  = (const float*)d_in[0];
  const float* Wq = (const float*)d_in[1];
  const float* bq = (const float*)d_in[2];
  const float* Wk = (const float*)d_in[3];
  const float* bk = (const float*)d_in[4];
  const float* Wv = (const float*)d_in[5];
  const float* bv = (const float*)d_in[6];
  const float* Wo = (const float*)d_in[7];
  const float* bo = (const float*)d_in[8];

  const int B = 8, S = 2048, E = 768;
  const int F = 3 * E;           // 2304 fused output features
  const long BS = (long)B * S;   // 16384

  char* ws = (char*)d_ws;
  unsigned short* x_bf = (unsigned short*)ws;  ws += BS * E * 2;       // 25.2 MB (also ctx)
  unsigned short* W3t  = (unsigned short*)ws;  ws += (long)F * E * 2;  // 3.5 MB  [2304][768]
  unsigned short* Wot  = (unsigned short*)ws;  ws += (long)E * E * 2;
  float*          bqkv = (float*)ws;           ws += 16384;            // 2304 floats (padded)
  unsigned short* QKVb = (unsigned short*)ws;  ws += BS * F * 2;       // 75.5 MB [16384][2304]
  unsigned short* Vt   = (unsigned short*)ws;  ws += BS * E * 2;       // 25.2 MB [B][E][S]
  unsigned short* Sb   = (unsigned short*)ws;  ws += (long)B * S * S * 2; // 67.1 MB
  unsigned short* Cx   = x_bf;  // ctx aliases x_bf (x_bf dead after QKV gemm)

  if (ws_size < (size_t)((char*)ws - (char*)d_ws)) return;

  const float rsE = 1.0f / sqrtf((float)E);

  cast_f32_bf16<<<(int)((BS * E) / 1024), 256, 0, stream>>>(x, x_bf, BS * E);
  dim3 tg(E / 64, E / 64, 4);
  transpose_cast_w4<<<tg, 256, 0, stream>>>(Wq, Wk, Wv, Wo,
                                            W3t, W3t + (long)E * E, W3t + (long)2 * E * E, Wot, E);
  hipMemcpyAsync(bqkv,         bq, E * sizeof(float), hipMemcpyDeviceToDevice, stream);
  hipMemcpyAsync(bqkv + E,     bk, E * sizeof(float), hipMemcpyDeviceToDevice, stream);
  hipMemcpyAsync(bqkv + 2 * E, bv, E * sizeof(float), hipMemcpyDeviceToDevice, stream);

  // fused QKV = x @ [Wq|Wk|Wv] + [bq|bk|bv] : M=16384 N=2304 K=768
  // fluid grid 9x64 = 576 blocks (2.25 rounds; beats any persistent split)
  // V-slice (n0>=1536) written transposed to Vt by the fused epilogue.
  dim3 gf(F / 256, (int)(BS / 256), 1);
  gemm_qkv<<<gf, 512, 0, stream>>>(x_bf, W3t, QKVb, bqkv, Vt,
                                   (int)BS, F, E, E, E, F,
                                   0, 0, 0, 1.0f);

  // Sb = Q K^T / sqrt(E) : strided views of QKVb (lda=ldb=2304)
  // hw grid 8x8x4 = 256 x NTILE=2 (ZEXT=1) -> 512 virtual (%8==0), 1 block/CU
  dim3 gs(S / 256, S / 256, B / 2);
  gemm_qk<<<gs, 512, 0, stream>>>(QKVb, QKVb + E, Sb, nullptr, nullptr,
                                  S, S, E, F, F, S,
                                  (long)S * F, (long)S * F, (long)S * S, rsE);

  softmax_rows<<<(int)BS, 256, 0, stream>>>(Sb, S);

  // ctx = softmax(S) @ V : M=2048 N=768 K=2048, grid 3x8x8 = 192
  dim3 gp(E / 256, S / 256, B);
  gemm_pv<<<gp, 512, 0, stream>>>(Sb, Vt, Cx, nullptr, nullptr,
                                  S, E, S, S, S, E,
                                  (long)S * S, (long)E * S, (long)S * E, 1.0f);

  // out = ctx @ Wo + bo (fp32 out) : grid 3x64 = 192
  dim3 g1(E / 256, (int)(BS / 256), 1);
  gemm_o<<<g1, 512, 0, stream>>>(Cx, Wot, (float*)d_out, bo, nullptr,
                                 (int)BS, E, E, E, E, E,
                                 0, 0, 0, 1.0f);
}

// Round 7
// 355.892 us; speedup vs baseline: 1.0855x; 1.0322x over previous
//
#include <hip/hip_runtime.h>
#include <hip/hip_bf16.h>

// Single-head self-attention, B=8 S=2048 E=768, fp32 in/out.
// R11: compose measured-best configs:
//   - gemm_qk back to FLUID grid 512 (R7's 355us config; R10's persistent
//     256x2 correlated with +12us on the non-qkv remainder)
//   - gemm_qkv fluid 576 with R10's verified body (81us, MfmaUtil 28)
//   - bias copies folded into transpose_cast_w4 (3 fewer launches)
// Body (8-phase, two-stage prologue, counted vmcnt(6), SFEN, setprio,
// XCD swizzle) byte-identical to R10.

using short8  = __attribute__((ext_vector_type(8))) short;
using floatx4 = __attribute__((ext_vector_type(4))) float;

typedef const __attribute__((address_space(1))) unsigned short* gas_us;
typedef __attribute__((address_space(3))) unsigned short* las_us;

__device__ __forceinline__ float bf2f(unsigned short u){
  union { unsigned int i; float f; } v; v.i = ((unsigned int)u) << 16; return v.f;
}
__device__ __forceinline__ unsigned short f2bf(float f){
  union { float f; unsigned int i; } v; v.f = f;
  unsigned int r = v.i + 0x7fffu + ((v.i >> 16) & 1u);   // RNE
  return (unsigned short)(r >> 16);
}

// ---------------- prep kernels ----------------

__global__ __launch_bounds__(256) void cast_f32_bf16(const float* __restrict__ in,
                                                     unsigned short* __restrict__ out,
                                                     long n){
  long i = ((long)blockIdx.x * 256 + threadIdx.x) * 4;
  if (i + 3 < n) {
    float4 v = *(const float4*)(in + i);
    uint2 o;
    o.x = (unsigned int)f2bf(v.x) | ((unsigned int)f2bf(v.y) << 16);
    o.y = (unsigned int)f2bf(v.z) | ((unsigned int)f2bf(v.w) << 16);
    *(uint2*)(out + i) = o;
  }
}

// 4 weight matrices [n x n] fp32 row-major -> bf16 transposed, one launch.
// Also copies the q/k/v biases into the concatenated bqkv buffer.
__global__ __launch_bounds__(256) void transpose_cast_w4(
    const float* __restrict__ W0, const float* __restrict__ W1,
    const float* __restrict__ W2, const float* __restrict__ W3,
    unsigned short* __restrict__ D0, unsigned short* __restrict__ D1,
    unsigned short* __restrict__ D2, unsigned short* __restrict__ D3,
    const float* __restrict__ b0, const float* __restrict__ b1,
    const float* __restrict__ b2, float* __restrict__ bqkv, int n){
  __shared__ float tile[64][65];
  const int z = blockIdx.z;
  const float* W = (z == 0) ? W0 : (z == 1) ? W1 : (z == 2) ? W2 : W3;
  unsigned short* Wt = (z == 0) ? D0 : (z == 1) ? D1 : (z == 2) ? D2 : D3;
  int bx = blockIdx.x * 64;     // f base
  int by = blockIdx.y * 64;     // e base
  int tx = threadIdx.x & 63;
  int ty = threadIdx.x >> 6;    // 0..3
  if (z < 3 && blockIdx.x == 0 && blockIdx.y == 0) {
    const float* bsrc = (z == 0) ? b0 : (z == 1) ? b1 : b2;
    #pragma unroll
    for (int i = threadIdx.x; i < 768; i += 256)
      bqkv[z * 768 + i] = bsrc[i];
  }
  #pragma unroll
  for (int r = ty; r < 64; r += 4)
    tile[r][tx] = W[(long)(by + r) * n + bx + tx];
  __syncthreads();
  #pragma unroll
  for (int r = ty; r < 64; r += 4)
    Wt[(long)(bx + r) * n + by + tx] = f2bf(tile[tx][r]);
}

// ---------------- 256x256 8-phase MFMA GEMM body ----------------
// C[m,n] = alpha * sum_k A[m,k]*Bt[n,k]  (+ bias[n])
// A  : bf16 [M x K] rows stride lda elements (batch stride sA)
// Bt : bf16 [N x K] rows stride ldb elements (batch stride sB)
// C  : bf16 or fp32 (OUTF), ldc leading dim (batch stride sC)
// VTFUSE: tiles with n0>=1536 write transposed to vt[B][E][S].
// NTILE: output tiles per block; ZEXT=1: virtual tiles extend z (batch),
//        ZEXT=0: virtual tiles extend the xy plane.
// Requires: M,N mult of 256; K mult of 128; (hw grid * NTILE) % 8 == 0.

union SMemU {
  struct { unsigned short A[2 * 256 * 64]; unsigned short B[2 * 256 * 64]; } ab;
  unsigned short T[256 * 256];
};

template<int BIASN, int OUTF, int VTFUSE, int NTILE, int ZEXT>
__device__ __forceinline__ void gemm256_body(
    const unsigned short* __restrict__ A,
    const unsigned short* __restrict__ Bt,
    void* __restrict__ Cout,
    const float* __restrict__ bias,
    unsigned short* __restrict__ vt,
    int M, int N, int K, int lda, int ldb, int ldc,
    long sA, long sB, long sC, float alpha)
{
  const int gx = gridDim.x, gy = gridDim.y;
  const int nxy = gx * gy;
  const int nwg_hw = nxy * (int)gridDim.z;
  const int nwgv = nwg_hw * NTILE;
  const int vnxy = ZEXT ? nxy : nxy * NTILE;   // xy-plane size of virtual grid
  const int hwflat = (int)blockIdx.x + gx * (int)blockIdx.y + nxy * (int)blockIdx.z;

  __shared__ __align__(16) SMemU sm;
  unsigned short* Asm = sm.ab.A;
  unsigned short* Bsm = sm.ab.B;

  const int tid  = threadIdx.x;
  const int l    = tid & 63;
  const int wv   = tid >> 6;        // 0..7
  const int wm   = wv >> 2;         // 0..1  (M half of block)
  const int wn   = wv & 3;          // 0..3  (N quarter)
  const int la   = l & 15;
  const int quad = l >> 4;
  const int c0   = quad ^ (l & 7);  // swizzled chunk (row&7 == la&7)

  const long ldaL = lda, ldbL = ldb;

  // staging geometry (loop-invariant)
  const int r8  = l >> 3;                 // 0..7
  const int cg  = (l & 7) ^ r8;           // pre-swizzled global chunk
  const int st0 = wv * 16, st1 = wv * 16 + 8;
  const int ar0 = (st0 >> 6) * 128 + (st0 & 63);
  const int ar1 = (st1 >> 6) * 128 + (st1 & 63);

  las_us dA0 = (las_us)&Asm[ar0 * 64];
  las_us dA1 = (las_us)&Asm[ar1 * 64];
  las_us dB0 = (las_us)&Bsm[ar0 * 64];
  las_us dB1 = (las_us)&Bsm[ar1 * 64];

  const short8* A8 = (const short8*)Asm;   // tile stride 2048 short8
  const short8* B8 = (const short8*)Bsm;
  const int rA = (wm * 128 + la) * 8;
  const int rB = (wn * 64  + la) * 8;

  const int NT = K >> 6;   // K % 128 == 0 so NT even
  const int NI = NT >> 1;

  // per-tile mutable state
  long m0, n0;
  int bz;
  const unsigned short *sA0, *sA1, *sB0, *sB1;

#define MKTILE(V) do{ int flat_ = (V); \
  if (!(nwgv & 7)) flat_ = (flat_ & 7) * (nwgv >> 3) + (flat_ >> 3); \
  bz = flat_ / vnxy; const int rxy_ = flat_ - bz * vnxy; \
  const int by_ = rxy_ / gx; const int bx_ = rxy_ - by_ * gx; \
  m0 = (long)by_ * 256; n0 = (long)bx_ * 256; \
  const unsigned short* Ab_ = A  + (long)bz * sA; \
  const unsigned short* Bb_ = Bt + (long)bz * sB; \
  sA0 = Ab_ + (m0 + ar0 + r8) * ldaL + cg * 8; \
  sA1 = Ab_ + (m0 + ar1 + r8) * ldaL + cg * 8; \
  sB0 = Bb_ + (n0 + ar0 + r8) * ldbL + cg * 8; \
  sB1 = Bb_ + (n0 + ar1 + r8) * ldbL + cg * 8; }while(0)

// stage one 128-row granule (2 x global_load_lds, 16B/lane, linear LDS dest)
#define STG(P0,P1,D0,D1,BO,G,KT,LD) do{ const long _ko=(long)(G)*64*(LD)+(long)(KT)*64; \
  __builtin_amdgcn_global_load_lds((gas_us)((P0)+_ko),(D0)+(BO)+(G)*4096,16,0,0);       \
  __builtin_amdgcn_global_load_lds((gas_us)((P1)+_ko),(D1)+(BO)+(G)*4096,16,0,0);}while(0)
// issue tile0->buf0 (4 granule-pairs) + tile1->buf1 (3 pairs), no waits
#define PROLOG_ISSUE do{ \
  STG(sA0,sA1,dA0,dA1,0,0,0,ldaL);      STG(sB0,sB1,dB0,dB1,0,0,0,ldbL);  \
  STG(sA0,sA1,dA0,dA1,0,1,0,ldaL);      STG(sB0,sB1,dB0,dB1,0,1,0,ldbL);  \
  STG(sA0,sA1,dA0,dA1,16384,0,1,ldaL);  STG(sB0,sB1,dB0,dB1,16384,0,1,ldbL); \
  STG(sA0,sA1,dA0,dA1,16384,1,1,ldaL); }while(0)
// ds_read_b128 fragment loads; BO in short8 units (0 or 2048)
#define LDA(BO,MH) { _Pragma("unroll") for (int mf=0; mf<4; mf++){ \
    a[mf][0]=A8[(BO)+rA+((MH)*4+mf)*128+c0]; a[mf][1]=A8[(BO)+rA+((MH)*4+mf)*128+(c0^4)]; } }
#define LDB(DST,BO,NH) { _Pragma("unroll") for (int nf=0; nf<2; nf++){ \
    DST[nf][0]=B8[(BO)+rB+((NH)*2+nf)*128+c0]; DST[nf][1]=B8[(BO)+rB+((NH)*2+nf)*128+(c0^4)]; } }
// 16 MFMA: one C quadrant x K=64
#define MM(MH,NH,BB) { _Pragma("unroll") for (int mf=0; mf<4; mf++) _Pragma("unroll") for (int nf=0; nf<2; nf++){ \
    acc[(MH)*4+mf][(NH)*2+nf]=__builtin_amdgcn_mfma_f32_16x16x32_bf16(a[mf][0],BB[nf][0],acc[(MH)*4+mf][(NH)*2+nf],0,0,0); \
    acc[(MH)*4+mf][(NH)*2+nf]=__builtin_amdgcn_mfma_f32_16x16x32_bf16(a[mf][1],BB[nf][1],acc[(MH)*4+mf][(NH)*2+nf],0,0,0); } }
#define BAR   __builtin_amdgcn_s_barrier()
#define WLG0  asm volatile("s_waitcnt lgkmcnt(0)")
#define SFEN  __builtin_amdgcn_sched_barrier(0)
#define PRIO1 __builtin_amdgcn_s_setprio(1)
#define PRIO0 __builtin_amdgcn_s_setprio(0)

  floatx4 acc[8][4];
  short8 a[4][2], b0[2][2], b1[2][2];

  // tile-0 prologue: R7's measured two-stage form
  MKTILE(hwflat);
  STG(sA0,sA1,dA0,dA1,0,0,0,ldaL);
  STG(sB0,sB1,dB0,dB1,0,0,0,ldbL);
  STG(sA0,sA1,dA0,dA1,0,1,0,ldaL);
  STG(sB0,sB1,dB0,dB1,0,1,0,ldbL);
  asm volatile("s_waitcnt vmcnt(4)");
  STG(sA0,sA1,dA0,dA1,16384,0,1,ldaL);
  STG(sB0,sB1,dB0,dB1,16384,0,1,ldbL);
  STG(sA0,sA1,dA0,dA1,16384,1,1,ldaL);

  #pragma unroll 1
  for (int tile = 0; tile < NTILE; ++tile) {
    #pragma unroll
    for (int i = 0; i < 8; i++)
      #pragma unroll
      for (int j = 0; j < 4; j++)
        #pragma unroll
        for (int r = 0; r < 4; r++) acc[i][j][r] = 0.0f;

    asm volatile("s_waitcnt vmcnt(6)");   // buf0 (8 oldest) complete
    BAR;

    for (int i = 0; i < NI; i++) {
      const int t1 = 2*i + 1;                                  // always < NT
      const int t2 = (2*i + 2 < NT) ? 2*i + 2 : NT - 1;        // clamped prefetch
      const int t3 = (2*i + 3 < NT) ? 2*i + 3 : NT - 1;

      // P1: read buf0 A-h0 (8) + B-h0 (4); stage buf1 B-g1 (tile t1)
      LDA(0,0); LDB(b0,0,0);
      STG(sB0,sB1,dB0,dB1,16384,1,t1,ldbL);
      asm volatile("s_waitcnt lgkmcnt(8)");
      BAR; WLG0; SFEN; PRIO1; MM(0,0,b0); PRIO0; SFEN; BAR;

      // P2: read buf0 B-h1 (4); stage buf0 A-g0 (tile t2)
      LDB(b1,0,1);
      STG(sA0,sA1,dA0,dA1,0,0,t2,ldaL);
      BAR; WLG0; SFEN; PRIO1; MM(0,1,b1); PRIO0; SFEN; BAR;

      // P3: read buf0 A-h1 (8); stage buf0 B-g0 (tile t2)
      LDA(0,1);
      STG(sB0,sB1,dB0,dB1,0,0,t2,ldbL);
      BAR; WLG0; SFEN; PRIO1; MM(1,1,b1); PRIO0; SFEN; BAR;

      // P4: no reads (b0 held); stage buf0 A-g1 (tile t2); counted vmcnt
      STG(sA0,sA1,dA0,dA1,0,1,t2,ldaL);
      BAR; WLG0; SFEN; PRIO1; MM(1,0,b0); PRIO0; SFEN;
      asm volatile("s_waitcnt vmcnt(6)");
      BAR;

      // P5: read buf1 A-h0 + B-h0; stage buf0 B-g1 (tile t2)
      LDA(2048,0); LDB(b0,2048,0);
      STG(sB0,sB1,dB0,dB1,0,1,t2,ldbL);
      asm volatile("s_waitcnt lgkmcnt(8)");
      BAR; WLG0; SFEN; PRIO1; MM(0,0,b0); PRIO0; SFEN; BAR;

      // P6: read buf1 B-h1; stage buf1 A-g0 (tile t3)
      LDB(b1,2048,1);
      STG(sA0,sA1,dA0,dA1,16384,0,t3,ldaL);
      BAR; WLG0; SFEN; PRIO1; MM(0,1,b1); PRIO0; SFEN; BAR;

      // P7: read buf1 A-h1; stage buf1 B-g0 (tile t3)
      LDA(2048,1);
      STG(sB0,sB1,dB0,dB1,16384,0,t3,ldbL);
      BAR; WLG0; SFEN; PRIO1; MM(1,1,b1); PRIO0; SFEN; BAR;

      // P8: no reads; stage buf1 A-g1 (tile t3); counted vmcnt
      STG(sA0,sA1,dA0,dA1,16384,1,t3,ldaL);
      BAR; WLG0; SFEN; PRIO1; MM(1,0,b0); PRIO0; SFEN;
      asm volatile("s_waitcnt vmcnt(6)");
      BAR;
    }

    asm volatile("s_waitcnt vmcnt(0)");   // drain dangling clamped prefetches
    // all waves past P8's closing BAR -> ds_reads drained; LDS reusable.
    const long em0 = m0, en0 = n0;
    const int  ebz = bz;
    const bool vtile = VTFUSE && (en0 >= 1536);
    if (NTILE > 1 && tile + 1 < NTILE && !vtile) {
      MKTILE(hwflat + (tile + 1) * nwg_hw);
      PROLOG_ISSUE;                       // hidden under the epilogue below
    }

    // ---- V-fused epilogue: transpose 256x256 tile through LDS -> Vt[B][E][S]
    if (vtile) {
      __syncthreads();
      unsigned short* T = sm.T;        // [256][256], XOR-swizzled columns
      #pragma unroll
      for (int mf = 0; mf < 8; mf++) {
        #pragma unroll
        for (int nf = 0; nf < 4; nf++) {
          const int ln = wn * 64 + nf * 16 + la;          // local n (Vt row)
          const int lm = wm * 128 + mf * 16 + quad * 4;   // local m (Vt col base)
          unsigned long long pk = 0;
          #pragma unroll
          for (int r = 0; r < 4; r++) {
            float v = acc[mf][nf][r] * alpha;
            if (BIASN) v += bias[en0 + ln];
            pk |= (unsigned long long)f2bf(v) << (16 * r);
          }
          *(unsigned long long*)&T[ln * 256 + (lm ^ ((ln & 7) << 3))] = pk;
        }
      }
      __syncthreads();
      const int b  = (int)(em0 >> 11);         // batch (2048 tokens each)
      const int s0 = (int)(em0 & 2047);
      const int e0 = (int)(en0 - 1536);
      unsigned short* dst = vt + (long)b * 768 * 2048 + (long)e0 * 2048 + s0;
      const int lr = tid >> 5;                 // 0..15
      const int c  = tid & 31;                 // 16B chunk within row
      #pragma unroll
      for (int i = 0; i < 16; i++) {
        const int ln = i * 16 + lr;
        short8 v = *(const short8*)&T[ln * 256 + ((c * 8) ^ ((ln & 7) << 3))];
        *(short8*)&dst[(long)ln * 2048 + c * 8] = v;
      }
      if (NTILE > 1 && tile + 1 < NTILE) {
        __syncthreads();                 // all waves done reading T
        MKTILE(hwflat + (tile + 1) * nwg_hw);
        PROLOG_ISSUE;                    // waited at next tile-top vmcnt(6)
      }
      continue;
    }

    // epilogue: C/D layout: n = la, m = quad*4 + reg   [measured m89/m91]
    float* Cf = (float*)Cout + (long)ebz * sC;
    unsigned short* Ch = (unsigned short*)Cout + (long)ebz * sC;
    #pragma unroll
    for (int mf = 0; mf < 8; mf++) {
      #pragma unroll
      for (int nf = 0; nf < 4; nf++) {
        #pragma unroll
        for (int r = 0; r < 4; r++) {
          long m = em0 + wm * 128 + mf * 16 + quad * 4 + r;
          long n = en0 + wn * 64  + nf * 16 + la;
          float v = acc[mf][nf][r] * alpha;
          if (BIASN) v += bias[n];
          long idx = m * (long)ldc + n;
          if (OUTF) Cf[idx] = v;
          else      Ch[idx] = f2bf(v);
        }
      }
    }
  }

#undef MKTILE
#undef STG
#undef PROLOG_ISSUE
#undef LDA
#undef LDB
#undef MM
#undef BAR
#undef WLG0
#undef SFEN
#undef PRIO1
#undef PRIO0
}

// ---- role-named kernels (distinct Kernel_Name in rocprof) ----
#define GEMM_ARGS const unsigned short* __restrict__ A, const unsigned short* __restrict__ Bt, \
    void* __restrict__ Cout, const float* __restrict__ bias, unsigned short* __restrict__ vt, \
    int M, int N, int K, int lda, int ldb, int ldc, long sA, long sB, long sC, float alpha
#define GEMM_PASS A, Bt, Cout, bias, vt, M, N, K, lda, ldb, ldc, sA, sB, sC, alpha

__global__ __launch_bounds__(512, 2) void gemm_qkv(GEMM_ARGS){ gemm256_body<1,0,1,1,0>(GEMM_PASS); }
__global__ __launch_bounds__(512, 2) void gemm_qk (GEMM_ARGS){ gemm256_body<0,0,0,1,1>(GEMM_PASS); }
__global__ __launch_bounds__(512, 2) void gemm_pv (GEMM_ARGS){ gemm256_body<0,0,0,1,1>(GEMM_PASS); }
__global__ __launch_bounds__(512, 2) void gemm_o  (GEMM_ARGS){ gemm256_body<1,1,0,1,1>(GEMM_PASS); }

// ---------------- row softmax (in-place, bf16) ----------------
__global__ __launch_bounds__(256) void softmax_rows(unsigned short* __restrict__ S, int cols){
  long row = blockIdx.x;
  unsigned short* p = S + row * (long)cols;
  int tid  = threadIdx.x;
  int wave = tid >> 6;
  int lane = tid & 63;

  uint4 raw = ((const uint4*)p)[tid];   // 8 bf16
  unsigned short* rs = (unsigned short*)&raw;
  float x[8];
  float mx = -1e30f;
  #pragma unroll
  for (int i = 0; i < 8; i++) { x[i] = bf2f(rs[i]); mx = fmaxf(mx, x[i]); }
  #pragma unroll
  for (int off = 32; off >= 1; off >>= 1) mx = fmaxf(mx, __shfl_xor(mx, off, 64));

  __shared__ float smax[4], ssum[4];
  if (lane == 0) smax[wave] = mx;
  __syncthreads();
  mx = fmaxf(fmaxf(smax[0], smax[1]), fmaxf(smax[2], smax[3]));

  float s = 0.0f;
  #pragma unroll
  for (int i = 0; i < 8; i++) { x[i] = __expf(x[i] - mx); s += x[i]; }
  #pragma unroll
  for (int off = 32; off >= 1; off >>= 1) s += __shfl_xor(s, off, 64);
  if (lane == 0) ssum[wave] = s;
  __syncthreads();
  s = ssum[0] + ssum[1] + ssum[2] + ssum[3];
  float inv = 1.0f / s;

  #pragma unroll
  for (int i = 0; i < 8; i++) rs[i] = f2bf(x[i] * inv);
  ((uint4*)p)[tid] = raw;
}

// ---------------- launch ----------------

extern "C" void kernel_launch(void* const* d_in, const int* in_sizes, int n_in,
                              void* d_out, int out_size, void* d_ws, size_t ws_size,
                              hipStream_t stream)
{
  const float* x  = (const float*)d_in[0];
  const float* Wq = (const float*)d_in[1];
  const float* bq = (const float*)d_in[2];
  const float* Wk = (const float*)d_in[3];
  const float* bk = (const float*)d_in[4];
  const float* Wv = (const float*)d_in[5];
  const float* bv = (const float*)d_in[6];
  const float* Wo = (const float*)d_in[7];
  const float* bo = (const float*)d_in[8];

  const int B = 8, S = 2048, E = 768;
  const int F = 3 * E;           // 2304 fused output features
  const long BS = (long)B * S;   // 16384

  char* ws = (char*)d_ws;
  unsigned short* x_bf = (unsigned short*)ws;  ws += BS * E * 2;       // 25.2 MB (also ctx)
  unsigned short* W3t  = (unsigned short*)ws;  ws += (long)F * E * 2;  // 3.5 MB  [2304][768]
  unsigned short* Wot  = (unsigned short*)ws;  ws += (long)E * E * 2;
  float*          bqkv = (float*)ws;           ws += 16384;            // 2304 floats (padded)
  unsigned short* QKVb = (unsigned short*)ws;  ws += BS * F * 2;       // 75.5 MB [16384][2304]
  unsigned short* Vt   = (unsigned short*)ws;  ws += BS * E * 2;       // 25.2 MB [B][E][S]
  unsigned short* Sb   = (unsigned short*)ws;  ws += (long)B * S * S * 2; // 67.1 MB
  unsigned short* Cx   = x_bf;  // ctx aliases x_bf (x_bf dead after QKV gemm)

  if (ws_size < (size_t)((char*)ws - (char*)d_ws)) return;

  const float rsE = 1.0f / sqrtf((float)E);

  cast_f32_bf16<<<(int)((BS * E) / 1024), 256, 0, stream>>>(x, x_bf, BS * E);
  dim3 tg(E / 64, E / 64, 4);
  transpose_cast_w4<<<tg, 256, 0, stream>>>(Wq, Wk, Wv, Wo,
                                            W3t, W3t + (long)E * E, W3t + (long)2 * E * E, Wot,
                                            bq, bk, bv, bqkv, E);

  // fused QKV = x @ [Wq|Wk|Wv] + [bq|bk|bv] : M=16384 N=2304 K=768
  // fluid grid 9x64 = 576 blocks (2.25 rounds)
  // V-slice (n0>=1536) written transposed to Vt by the fused epilogue.
  dim3 gf(F / 256, (int)(BS / 256), 1);
  gemm_qkv<<<gf, 512, 0, stream>>>(x_bf, W3t, QKVb, bqkv, Vt,
                                   (int)BS, F, E, E, E, F,
                                   0, 0, 0, 1.0f);

  // Sb = Q K^T / sqrt(E) : strided views of QKVb (lda=ldb=2304)
  // fluid grid 8x8x8 = 512 (R7's measured-best config; one batch per XCD)
  dim3 gs(S / 256, S / 256, B);
  gemm_qk<<<gs, 512, 0, stream>>>(QKVb, QKVb + E, Sb, nullptr, nullptr,
                                  S, S, E, F, F, S,
                                  (long)S * F, (long)S * F, (long)S * S, rsE);

  softmax_rows<<<(int)BS, 256, 0, stream>>>(Sb, S);

  // ctx = softmax(S) @ V : M=2048 N=768 K=2048, grid 3x8x8 = 192
  dim3 gp(E / 256, S / 256, B);
  gemm_pv<<<gp, 512, 0, stream>>>(Sb, Vt, Cx, nullptr, nullptr,
                                  S, E, S, S, S, E,
                                  (long)S * S, (long)E * S, (long)S * E, 1.0f);

  // out = ctx @ Wo + bo (fp32 out) : grid 3x64 = 192
  dim3 g1(E / 256, (int)(BS / 256), 1);
  gemm_o<<<g1, 512, 0, stream>>>(Cx, Wot, (float*)d_out, bo, nullptr,
                                 (int)BS, E, E, E, E, E,
                                 0, 0, 0, 1.0f);
}

// Round 8
// 352.276 us; speedup vs baseline: 1.0967x; 1.0103x over previous
//
#include <hip/hip_runtime.h>
#include <hip/hip_bf16.h>

// Single-head self-attention, B=8 S=2048 E=768, fp32 in/out.
// R12: R11 (measured-best: fluid qkv 576, fluid qk 512, pv/o 192) with the
//      two prep kernels merged into ONE launch (cast x 12288 blocks ++
//      transpose-weights 576 blocks run concurrently; one launch gap
//      removed). GEMM bodies byte-identical to R11.

using short8  = __attribute__((ext_vector_type(8))) short;
using floatx4 = __attribute__((ext_vector_type(4))) float;

typedef const __attribute__((address_space(1))) unsigned short* gas_us;
typedef __attribute__((address_space(3))) unsigned short* las_us;

__device__ __forceinline__ float bf2f(unsigned short u){
  union { unsigned int i; float f; } v; v.i = ((unsigned int)u) << 16; return v.f;
}
__device__ __forceinline__ unsigned short f2bf(float f){
  union { float f; unsigned int i; } v; v.f = f;
  unsigned int r = v.i + 0x7fffu + ((v.i >> 16) & 1u);   // RNE
  return (unsigned short)(r >> 16);
}

// ---------------- merged prep kernel ----------------
// blocks [0, NC)         : cast x f32 -> x_bf bf16 (1024 elems/block)
// blocks [NC, NC+4*144)  : 64x64 transpose-cast tiles of Wq/Wk/Wv/Wo
//                          (+ bias concat on the first tile of each of q/k/v)
__global__ __launch_bounds__(256) void prep_all(
    const float* __restrict__ x, unsigned short* __restrict__ x_bf, long n,
    const float* __restrict__ W0, const float* __restrict__ W1,
    const float* __restrict__ W2, const float* __restrict__ W3,
    unsigned short* __restrict__ D0, unsigned short* __restrict__ D1,
    unsigned short* __restrict__ D2, unsigned short* __restrict__ D3,
    const float* __restrict__ b0, const float* __restrict__ b1,
    const float* __restrict__ b2, float* __restrict__ bqkv,
    int wN, int NC)
{
  __shared__ float tile[64][65];
  const int bid = blockIdx.x;
  if (bid < NC) {                       // ---- cast path
    long i = ((long)bid * 256 + threadIdx.x) * 4;
    if (i + 3 < n) {
      float4 v = *(const float4*)(x + i);
      uint2 o;
      o.x = (unsigned int)f2bf(v.x) | ((unsigned int)f2bf(v.y) << 16);
      o.y = (unsigned int)f2bf(v.z) | ((unsigned int)f2bf(v.w) << 16);
      *(uint2*)(x_bf + i) = o;
    }
    return;
  }
  // ---- weight transpose path
  const int j   = bid - NC;
  const int z   = j / 144;              // 12x12 tiles per 768x768 weight
  const int rem = j - z * 144;
  const int bxt = rem % 12;
  const int byt = rem / 12;
  const float* W = (z == 0) ? W0 : (z == 1) ? W1 : (z == 2) ? W2 : W3;
  unsigned short* Wt = (z == 0) ? D0 : (z == 1) ? D1 : (z == 2) ? D2 : D3;
  const int bx = bxt * 64;              // f base
  const int by = byt * 64;              // e base
  const int tx = threadIdx.x & 63;
  const int ty = threadIdx.x >> 6;      // 0..3
  if (z < 3 && bxt == 0 && byt == 0) {
    const float* bsrc = (z == 0) ? b0 : (z == 1) ? b1 : b2;
    #pragma unroll
    for (int i = threadIdx.x; i < 768; i += 256)
      bqkv[z * 768 + i] = bsrc[i];
  }
  #pragma unroll
  for (int r = ty; r < 64; r += 4)
    tile[r][tx] = W[(long)(by + r) * wN + bx + tx];
  __syncthreads();
  #pragma unroll
  for (int r = ty; r < 64; r += 4)
    Wt[(long)(bx + r) * wN + by + tx] = f2bf(tile[tx][r]);
}

// ---------------- 256x256 8-phase MFMA GEMM body ----------------
// C[m,n] = alpha * sum_k A[m,k]*Bt[n,k]  (+ bias[n])
// A  : bf16 [M x K] rows stride lda elements (batch stride sA)
// Bt : bf16 [N x K] rows stride ldb elements (batch stride sB)
// C  : bf16 or fp32 (OUTF), ldc leading dim (batch stride sC)
// VTFUSE: tiles with n0>=1536 write transposed to vt[B][E][S].
// NTILE: output tiles per block; ZEXT=1: virtual tiles extend z (batch),
//        ZEXT=0: virtual tiles extend the xy plane.
// Requires: M,N mult of 256; K mult of 128; (hw grid * NTILE) % 8 == 0.

union SMemU {
  struct { unsigned short A[2 * 256 * 64]; unsigned short B[2 * 256 * 64]; } ab;
  unsigned short T[256 * 256];
};

template<int BIASN, int OUTF, int VTFUSE, int NTILE, int ZEXT>
__device__ __forceinline__ void gemm256_body(
    const unsigned short* __restrict__ A,
    const unsigned short* __restrict__ Bt,
    void* __restrict__ Cout,
    const float* __restrict__ bias,
    unsigned short* __restrict__ vt,
    int M, int N, int K, int lda, int ldb, int ldc,
    long sA, long sB, long sC, float alpha)
{
  const int gx = gridDim.x, gy = gridDim.y;
  const int nxy = gx * gy;
  const int nwg_hw = nxy * (int)gridDim.z;
  const int nwgv = nwg_hw * NTILE;
  const int vnxy = ZEXT ? nxy : nxy * NTILE;   // xy-plane size of virtual grid
  const int hwflat = (int)blockIdx.x + gx * (int)blockIdx.y + nxy * (int)blockIdx.z;

  __shared__ __align__(16) SMemU sm;
  unsigned short* Asm = sm.ab.A;
  unsigned short* Bsm = sm.ab.B;

  const int tid  = threadIdx.x;
  const int l    = tid & 63;
  const int wv   = tid >> 6;        // 0..7
  const int wm   = wv >> 2;         // 0..1  (M half of block)
  const int wn   = wv & 3;          // 0..3  (N quarter)
  const int la   = l & 15;
  const int quad = l >> 4;
  const int c0   = quad ^ (l & 7);  // swizzled chunk (row&7 == la&7)

  const long ldaL = lda, ldbL = ldb;

  // staging geometry (loop-invariant)
  const int r8  = l >> 3;                 // 0..7
  const int cg  = (l & 7) ^ r8;           // pre-swizzled global chunk
  const int st0 = wv * 16, st1 = wv * 16 + 8;
  const int ar0 = (st0 >> 6) * 128 + (st0 & 63);
  const int ar1 = (st1 >> 6) * 128 + (st1 & 63);

  las_us dA0 = (las_us)&Asm[ar0 * 64];
  las_us dA1 = (las_us)&Asm[ar1 * 64];
  las_us dB0 = (las_us)&Bsm[ar0 * 64];
  las_us dB1 = (las_us)&Bsm[ar1 * 64];

  const short8* A8 = (const short8*)Asm;   // tile stride 2048 short8
  const short8* B8 = (const short8*)Bsm;
  const int rA = (wm * 128 + la) * 8;
  const int rB = (wn * 64  + la) * 8;

  const int NT = K >> 6;   // K % 128 == 0 so NT even
  const int NI = NT >> 1;

  // per-tile mutable state
  long m0, n0;
  int bz;
  const unsigned short *sA0, *sA1, *sB0, *sB1;

#define MKTILE(V) do{ int flat_ = (V); \
  if (!(nwgv & 7)) flat_ = (flat_ & 7) * (nwgv >> 3) + (flat_ >> 3); \
  bz = flat_ / vnxy; const int rxy_ = flat_ - bz * vnxy; \
  const int by_ = rxy_ / gx; const int bx_ = rxy_ - by_ * gx; \
  m0 = (long)by_ * 256; n0 = (long)bx_ * 256; \
  const unsigned short* Ab_ = A  + (long)bz * sA; \
  const unsigned short* Bb_ = Bt + (long)bz * sB; \
  sA0 = Ab_ + (m0 + ar0 + r8) * ldaL + cg * 8; \
  sA1 = Ab_ + (m0 + ar1 + r8) * ldaL + cg * 8; \
  sB0 = Bb_ + (n0 + ar0 + r8) * ldbL + cg * 8; \
  sB1 = Bb_ + (n0 + ar1 + r8) * ldbL + cg * 8; }while(0)

// stage one 128-row granule (2 x global_load_lds, 16B/lane, linear LDS dest)
#define STG(P0,P1,D0,D1,BO,G,KT,LD) do{ const long _ko=(long)(G)*64*(LD)+(long)(KT)*64; \
  __builtin_amdgcn_global_load_lds((gas_us)((P0)+_ko),(D0)+(BO)+(G)*4096,16,0,0);       \
  __builtin_amdgcn_global_load_lds((gas_us)((P1)+_ko),(D1)+(BO)+(G)*4096,16,0,0);}while(0)
// issue tile0->buf0 (4 granule-pairs) + tile1->buf1 (3 pairs), no waits
#define PROLOG_ISSUE do{ \
  STG(sA0,sA1,dA0,dA1,0,0,0,ldaL);      STG(sB0,sB1,dB0,dB1,0,0,0,ldbL);  \
  STG(sA0,sA1,dA0,dA1,0,1,0,ldaL);      STG(sB0,sB1,dB0,dB1,0,1,0,ldbL);  \
  STG(sA0,sA1,dA0,dA1,16384,0,1,ldaL);  STG(sB0,sB1,dB0,dB1,16384,0,1,ldbL); \
  STG(sA0,sA1,dA0,dA1,16384,1,1,ldaL); }while(0)
// ds_read_b128 fragment loads; BO in short8 units (0 or 2048)
#define LDA(BO,MH) { _Pragma("unroll") for (int mf=0; mf<4; mf++){ \
    a[mf][0]=A8[(BO)+rA+((MH)*4+mf)*128+c0]; a[mf][1]=A8[(BO)+rA+((MH)*4+mf)*128+(c0^4)]; } }
#define LDB(DST,BO,NH) { _Pragma("unroll") for (int nf=0; nf<2; nf++){ \
    DST[nf][0]=B8[(BO)+rB+((NH)*2+nf)*128+c0]; DST[nf][1]=B8[(BO)+rB+((NH)*2+nf)*128+(c0^4)]; } }
// 16 MFMA: one C quadrant x K=64
#define MM(MH,NH,BB) { _Pragma("unroll") for (int mf=0; mf<4; mf++) _Pragma("unroll") for (int nf=0; nf<2; nf++){ \
    acc[(MH)*4+mf][(NH)*2+nf]=__builtin_amdgcn_mfma_f32_16x16x32_bf16(a[mf][0],BB[nf][0],acc[(MH)*4+mf][(NH)*2+nf],0,0,0); \
    acc[(MH)*4+mf][(NH)*2+nf]=__builtin_amdgcn_mfma_f32_16x16x32_bf16(a[mf][1],BB[nf][1],acc[(MH)*4+mf][(NH)*2+nf],0,0,0); } }
#define BAR   __builtin_amdgcn_s_barrier()
#define WLG0  asm volatile("s_waitcnt lgkmcnt(0)")
#define SFEN  __builtin_amdgcn_sched_barrier(0)
#define PRIO1 __builtin_amdgcn_s_setprio(1)
#define PRIO0 __builtin_amdgcn_s_setprio(0)

  floatx4 acc[8][4];
  short8 a[4][2], b0[2][2], b1[2][2];

  // tile-0 prologue: R7's measured two-stage form
  MKTILE(hwflat);
  STG(sA0,sA1,dA0,dA1,0,0,0,ldaL);
  STG(sB0,sB1,dB0,dB1,0,0,0,ldbL);
  STG(sA0,sA1,dA0,dA1,0,1,0,ldaL);
  STG(sB0,sB1,dB0,dB1,0,1,0,ldbL);
  asm volatile("s_waitcnt vmcnt(4)");
  STG(sA0,sA1,dA0,dA1,16384,0,1,ldaL);
  STG(sB0,sB1,dB0,dB1,16384,0,1,ldbL);
  STG(sA0,sA1,dA0,dA1,16384,1,1,ldaL);

  #pragma unroll 1
  for (int tile = 0; tile < NTILE; ++tile) {
    #pragma unroll
    for (int i = 0; i < 8; i++)
      #pragma unroll
      for (int j = 0; j < 4; j++)
        #pragma unroll
        for (int r = 0; r < 4; r++) acc[i][j][r] = 0.0f;

    asm volatile("s_waitcnt vmcnt(6)");   // buf0 (8 oldest) complete
    BAR;

    for (int i = 0; i < NI; i++) {
      const int t1 = 2*i + 1;                                  // always < NT
      const int t2 = (2*i + 2 < NT) ? 2*i + 2 : NT - 1;        // clamped prefetch
      const int t3 = (2*i + 3 < NT) ? 2*i + 3 : NT - 1;

      // P1: read buf0 A-h0 (8) + B-h0 (4); stage buf1 B-g1 (tile t1)
      LDA(0,0); LDB(b0,0,0);
      STG(sB0,sB1,dB0,dB1,16384,1,t1,ldbL);
      asm volatile("s_waitcnt lgkmcnt(8)");
      BAR; WLG0; SFEN; PRIO1; MM(0,0,b0); PRIO0; SFEN; BAR;

      // P2: read buf0 B-h1 (4); stage buf0 A-g0 (tile t2)
      LDB(b1,0,1);
      STG(sA0,sA1,dA0,dA1,0,0,t2,ldaL);
      BAR; WLG0; SFEN; PRIO1; MM(0,1,b1); PRIO0; SFEN; BAR;

      // P3: read buf0 A-h1 (8); stage buf0 B-g0 (tile t2)
      LDA(0,1);
      STG(sB0,sB1,dB0,dB1,0,0,t2,ldbL);
      BAR; WLG0; SFEN; PRIO1; MM(1,1,b1); PRIO0; SFEN; BAR;

      // P4: no reads (b0 held); stage buf0 A-g1 (tile t2); counted vmcnt
      STG(sA0,sA1,dA0,dA1,0,1,t2,ldaL);
      BAR; WLG0; SFEN; PRIO1; MM(1,0,b0); PRIO0; SFEN;
      asm volatile("s_waitcnt vmcnt(6)");
      BAR;

      // P5: read buf1 A-h0 + B-h0; stage buf0 B-g1 (tile t2)
      LDA(2048,0); LDB(b0,2048,0);
      STG(sB0,sB1,dB0,dB1,0,1,t2,ldbL);
      asm volatile("s_waitcnt lgkmcnt(8)");
      BAR; WLG0; SFEN; PRIO1; MM(0,0,b0); PRIO0; SFEN; BAR;

      // P6: read buf1 B-h1; stage buf1 A-g0 (tile t3)
      LDB(b1,2048,1);
      STG(sA0,sA1,dA0,dA1,16384,0,t3,ldaL);
      BAR; WLG0; SFEN; PRIO1; MM(0,1,b1); PRIO0; SFEN; BAR;

      // P7: read buf1 A-h1; stage buf1 B-g0 (tile t3)
      LDA(2048,1);
      STG(sB0,sB1,dB0,dB1,16384,0,t3,ldbL);
      BAR; WLG0; SFEN; PRIO1; MM(1,1,b1); PRIO0; SFEN; BAR;

      // P8: no reads; stage buf1 A-g1 (tile t3); counted vmcnt
      STG(sA0,sA1,dA0,dA1,16384,1,t3,ldaL);
      BAR; WLG0; SFEN; PRIO1; MM(1,0,b0); PRIO0; SFEN;
      asm volatile("s_waitcnt vmcnt(6)");
      BAR;
    }

    asm volatile("s_waitcnt vmcnt(0)");   // drain dangling clamped prefetches
    // all waves past P8's closing BAR -> ds_reads drained; LDS reusable.
    const long em0 = m0, en0 = n0;
    const int  ebz = bz;
    const bool vtile = VTFUSE && (en0 >= 1536);
    if (NTILE > 1 && tile + 1 < NTILE && !vtile) {
      MKTILE(hwflat + (tile + 1) * nwg_hw);
      PROLOG_ISSUE;                       // hidden under the epilogue below
    }

    // ---- V-fused epilogue: transpose 256x256 tile through LDS -> Vt[B][E][S]
    if (vtile) {
      __syncthreads();
      unsigned short* T = sm.T;        // [256][256], XOR-swizzled columns
      #pragma unroll
      for (int mf = 0; mf < 8; mf++) {
        #pragma unroll
        for (int nf = 0; nf < 4; nf++) {
          const int ln = wn * 64 + nf * 16 + la;          // local n (Vt row)
          const int lm = wm * 128 + mf * 16 + quad * 4;   // local m (Vt col base)
          unsigned long long pk = 0;
          #pragma unroll
          for (int r = 0; r < 4; r++) {
            float v = acc[mf][nf][r] * alpha;
            if (BIASN) v += bias[en0 + ln];
            pk |= (unsigned long long)f2bf(v) << (16 * r);
          }
          *(unsigned long long*)&T[ln * 256 + (lm ^ ((ln & 7) << 3))] = pk;
        }
      }
      __syncthreads();
      const int b  = (int)(em0 >> 11);         // batch (2048 tokens each)
      const int s0 = (int)(em0 & 2047);
      const int e0 = (int)(en0 - 1536);
      unsigned short* dst = vt + (long)b * 768 * 2048 + (long)e0 * 2048 + s0;
      const int lr = tid >> 5;                 // 0..15
      const int c  = tid & 31;                 // 16B chunk within row
      #pragma unroll
      for (int i = 0; i < 16; i++) {
        const int ln = i * 16 + lr;
        short8 v = *(const short8*)&T[ln * 256 + ((c * 8) ^ ((ln & 7) << 3))];
        *(short8*)&dst[(long)ln * 2048 + c * 8] = v;
      }
      if (NTILE > 1 && tile + 1 < NTILE) {
        __syncthreads();                 // all waves done reading T
        MKTILE(hwflat + (tile + 1) * nwg_hw);
        PROLOG_ISSUE;                    // waited at next tile-top vmcnt(6)
      }
      continue;
    }

    // epilogue: C/D layout: n = la, m = quad*4 + reg   [measured m89/m91]
    float* Cf = (float*)Cout + (long)ebz * sC;
    unsigned short* Ch = (unsigned short*)Cout + (long)ebz * sC;
    #pragma unroll
    for (int mf = 0; mf < 8; mf++) {
      #pragma unroll
      for (int nf = 0; nf < 4; nf++) {
        #pragma unroll
        for (int r = 0; r < 4; r++) {
          long m = em0 + wm * 128 + mf * 16 + quad * 4 + r;
          long n = en0 + wn * 64  + nf * 16 + la;
          float v = acc[mf][nf][r] * alpha;
          if (BIASN) v += bias[n];
          long idx = m * (long)ldc + n;
          if (OUTF) Cf[idx] = v;
          else      Ch[idx] = f2bf(v);
        }
      }
    }
  }

#undef MKTILE
#undef STG
#undef PROLOG_ISSUE
#undef LDA
#undef LDB
#undef MM
#undef BAR
#undef WLG0
#undef SFEN
#undef PRIO1
#undef PRIO0
}

// ---- role-named kernels (distinct Kernel_Name in rocprof) ----
#define GEMM_ARGS const unsigned short* __restrict__ A, const unsigned short* __restrict__ Bt, \
    void* __restrict__ Cout, const float* __restrict__ bias, unsigned short* __restrict__ vt, \
    int M, int N, int K, int lda, int ldb, int ldc, long sA, long sB, long sC, float alpha
#define GEMM_PASS A, Bt, Cout, bias, vt, M, N, K, lda, ldb, ldc, sA, sB, sC, alpha

__global__ __launch_bounds__(512, 2) void gemm_qkv(GEMM_ARGS){ gemm256_body<1,0,1,1,0>(GEMM_PASS); }
__global__ __launch_bounds__(512, 2) void gemm_qk (GEMM_ARGS){ gemm256_body<0,0,0,1,1>(GEMM_PASS); }
__global__ __launch_bounds__(512, 2) void gemm_pv (GEMM_ARGS){ gemm256_body<0,0,0,1,1>(GEMM_PASS); }
__global__ __launch_bounds__(512, 2) void gemm_o  (GEMM_ARGS){ gemm256_body<1,1,0,1,1>(GEMM_PASS); }

// ---------------- row softmax (in-place, bf16) ----------------
__global__ __launch_bounds__(256) void softmax_rows(unsigned short* __restrict__ S, int cols){
  long row = blockIdx.x;
  unsigned short* p = S + row * (long)cols;
  int tid  = threadIdx.x;
  int wave = tid >> 6;
  int lane = tid & 63;

  uint4 raw = ((const uint4*)p)[tid];   // 8 bf16
  unsigned short* rs = (unsigned short*)&raw;
  float x[8];
  float mx = -1e30f;
  #pragma unroll
  for (int i = 0; i < 8; i++) { x[i] = bf2f(rs[i]); mx = fmaxf(mx, x[i]); }
  #pragma unroll
  for (int off = 32; off >= 1; off >>= 1) mx = fmaxf(mx, __shfl_xor(mx, off, 64));

  __shared__ float smax[4], ssum[4];
  if (lane == 0) smax[wave] = mx;
  __syncthreads();
  mx = fmaxf(fmaxf(smax[0], smax[1]), fmaxf(smax[2], smax[3]));

  float s = 0.0f;
  #pragma unroll
  for (int i = 0; i < 8; i++) { x[i] = __expf(x[i] - mx); s += x[i]; }
  #pragma unroll
  for (int off = 32; off >= 1; off >>= 1) s += __shfl_xor(s, off, 64);
  if (lane == 0) ssum[wave] = s;
  __syncthreads();
  s = ssum[0] + ssum[1] + ssum[2] + ssum[3];
  float inv = 1.0f / s;

  #pragma unroll
  for (int i = 0; i < 8; i++) rs[i] = f2bf(x[i] * inv);
  ((uint4*)p)[tid] = raw;
}

// ---------------- launch ----------------

extern "C" void kernel_launch(void* const* d_in, const int* in_sizes, int n_in,
                              void* d_out, int out_size, void* d_ws, size_t ws_size,
                              hipStream_t stream)
{
  const float* x  = (const float*)d_in[0];
  const float* Wq = (const float*)d_in[1];
  const float* bq = (const float*)d_in[2];
  const float* Wk = (const float*)d_in[3];
  const float* bk = (const float*)d_in[4];
  const float* Wv = (const float*)d_in[5];
  const float* bv = (const float*)d_in[6];
  const float* Wo = (const float*)d_in[7];
  const float* bo = (const float*)d_in[8];

  const int B = 8, S = 2048, E = 768;
  const int F = 3 * E;           // 2304 fused output features
  const long BS = (long)B * S;   // 16384

  char* ws = (char*)d_ws;
  unsigned short* x_bf = (unsigned short*)ws;  ws += BS * E * 2;       // 25.2 MB (also ctx)
  unsigned short* W3t  = (unsigned short*)ws;  ws += (long)F * E * 2;  // 3.5 MB  [2304][768]
  unsigned short* Wot  = (unsigned short*)ws;  ws += (long)E * E * 2;
  float*          bqkv = (float*)ws;           ws += 16384;            // 2304 floats (padded)
  unsigned short* QKVb = (unsigned short*)ws;  ws += BS * F * 2;       // 75.5 MB [16384][2304]
  unsigned short* Vt   = (unsigned short*)ws;  ws += BS * E * 2;       // 25.2 MB [B][E][S]
  unsigned short* Sb   = (unsigned short*)ws;  ws += (long)B * S * S * 2; // 67.1 MB
  unsigned short* Cx   = x_bf;  // ctx aliases x_bf (x_bf dead after QKV gemm)

  if (ws_size < (size_t)((char*)ws - (char*)d_ws)) return;

  const float rsE = 1.0f / sqrtf((float)E);

  // merged prep: cast (12288 blocks) ++ 4 weight transposes (576 blocks)
  const int NC = (int)((BS * E) / 1024);
  prep_all<<<NC + 4 * 144, 256, 0, stream>>>(
      x, x_bf, BS * E,
      Wq, Wk, Wv, Wo,
      W3t, W3t + (long)E * E, W3t + (long)2 * E * E, Wot,
      bq, bk, bv, bqkv, E, NC);

  // fused QKV = x @ [Wq|Wk|Wv] + [bq|bk|bv] : M=16384 N=2304 K=768
  // fluid grid 9x64 = 576 blocks (2.25 rounds)
  // V-slice (n0>=1536) written transposed to Vt by the fused epilogue.
  dim3 gf(F / 256, (int)(BS / 256), 1);
  gemm_qkv<<<gf, 512, 0, stream>>>(x_bf, W3t, QKVb, bqkv, Vt,
                                   (int)BS, F, E, E, E, F,
                                   0, 0, 0, 1.0f);

  // Sb = Q K^T / sqrt(E) : strided views of QKVb (lda=ldb=2304)
  // fluid grid 8x8x8 = 512 (one batch per XCD)
  dim3 gs(S / 256, S / 256, B);
  gemm_qk<<<gs, 512, 0, stream>>>(QKVb, QKVb + E, Sb, nullptr, nullptr,
                                  S, S, E, F, F, S,
                                  (long)S * F, (long)S * F, (long)S * S, rsE);

  softmax_rows<<<(int)BS, 256, 0, stream>>>(Sb, S);

  // ctx = softmax(S) @ V : M=2048 N=768 K=2048, grid 3x8x8 = 192
  dim3 gp(E / 256, S / 256, B);
  gemm_pv<<<gp, 512, 0, stream>>>(Sb, Vt, Cx, nullptr, nullptr,
                                  S, E, S, S, S, E,
                                  (long)S * S, (long)E * S, (long)S * E, 1.0f);

  // out = ctx @ Wo + bo (fp32 out) : grid 3x64 = 192
  dim3 g1(E / 256, (int)(BS / 256), 1);
  gemm_o<<<g1, 512, 0, stream>>>(Cx, Wot, (float*)d_out, bo, nullptr,
                                 (int)BS, E, E, E, E, E,
                                 0, 0, 0, 1.0f);
}